// Round 10
// baseline (4415.579 us; speedup 1.0000x reference)
//
#include <hip/hip_runtime.h>
#include <hip/hip_bf16.h>

// Problem constants (from reference): T=8192 steps, batch=1, H=21 hidden.
#define T_LEN 8192
#define HDIM  21
#define GDIM  84           // 4*H gate rows
#define NGRP  (T_LEN / 4)  // 2048 groups of 4 timesteps
#define GSTRIDE (GDIM * 4) // 336 floats per group block
#define NIT   (NGRP + 1)   // fused loop: one extra group for the 1-step lag

// Workspace layout (floats):
//  zxG1[2048*336] zxG2[2048*336]  (GROUPED: [t/4][row][4])
//  h3[8192*21] M1[84*21] M2[84*21] b3p[84]
// NOTE: waves 0/1 prefetch up to 2 groups (2.7KB) past their zx buffer's end;
// the following ws region is mapped, values never consumed.

__device__ __forceinline__ float sigm(float x) {
    return 1.0f / (1.0f + __expf(-x));   // stable both directions
}
__device__ __forceinline__ float tanh_stable(float x) {
    float e = __expf(2.0f * x);          // +inf -> 1, -inf -> -1, no inf/inf
    return 1.0f - 2.0f / (e + 1.0f);
}

// ---------------------------------------------------------------------------
// K1: parallel input projections, GROUPED output zxG[g][j][q] (coalesced).
// ---------------------------------------------------------------------------
__global__ void zx12_kernel(const float* __restrict__ src,
                            const float* __restrict__ Wih1, const float* __restrict__ b1,
                            const float* __restrict__ Wih2, const float* __restrict__ b2,
                            float* __restrict__ zxG1, float* __restrict__ zxG2)
{
    int n = blockIdx.x * blockDim.x + threadIdx.x;
    if (n >= T_LEN * GDIM) return;
    unsigned g = (unsigned)n / GSTRIDE;
    unsigned r = (unsigned)n - g * GSTRIDE;
    unsigned j = r >> 2;
    unsigned t = (g << 2) | (r & 3);
    float4 s = *reinterpret_cast<const float4*>(src + 4 * t);
    float z1 = b1[j];
    z1 = __builtin_fmaf(Wih1[j * 3 + 0], s.x, z1);
    z1 = __builtin_fmaf(Wih1[j * 3 + 1], s.z, z1);
    z1 = __builtin_fmaf(Wih1[j * 3 + 2], s.w, z1);
    float z2 = b2[j];
    z2 = __builtin_fmaf(Wih2[j * 3 + 0], s.y, z2);
    z2 = __builtin_fmaf(Wih2[j * 3 + 1], s.z, z2);
    z2 = __builtin_fmaf(Wih2[j * 3 + 2], s.w, z2);
    zxG1[n] = z1;
    zxG2[n] = z2;
}

// ---------------------------------------------------------------------------
// K2: fold linear layers into LSTM3's input projection.
// M1[j,k] = Wih3[j,0]*W1[0,k] ; M2[j,k] = sum_m Wih3[j,1+m]*W2[m,k]
// b3p[j]  = b3[j] + Wih3[j,0]*bl1 + sum_m Wih3[j,1+m]*bl2[m]
// ---------------------------------------------------------------------------
__global__ void fold_kernel(const float* __restrict__ Wih3,
                            const float* __restrict__ W1, const float* __restrict__ bl1,
                            const float* __restrict__ W2, const float* __restrict__ bl2,
                            const float* __restrict__ b3,
                            float* __restrict__ M1, float* __restrict__ M2,
                            float* __restrict__ b3p)
{
    int idx = blockIdx.x * blockDim.x + threadIdx.x;
    if (idx < GDIM * HDIM) {
        int j = idx / HDIM, k = idx - j * HDIM;
        M1[idx] = Wih3[j * 50 + 0] * W1[k];
        float s = 0.0f;
        for (int m = 0; m < 49; ++m)
            s = __builtin_fmaf(Wih3[j * 50 + 1 + m], W2[m * HDIM + k], s);
        M2[idx] = s;
    }
    if (idx < GDIM) {
        float s = b3[idx] + Wih3[idx * 50 + 0] * bl1[0];
        for (int m = 0; m < 49; ++m)
            s = __builtin_fmaf(Wih3[idx * 50 + 1 + m], bl2[m], s);
        b3p[idx] = s;
    }
}

// ---------------------------------------------------------------------------
// K3: FUSED 3-LSTM pipelined scan. One block, 3 waves:
//   wave0 = LSTM1 (+ M1*h1 projection into LDS)
//   wave1 = LSTM2 (+ M2*h2 projection into LDS)
//   wave2 = LSTM3, one step behind, assembling zx3 from LDS partials.
// Per-wave lane map (as before):
//   lane k   (k<21): rowA=k (i,sig), rowB=42+k (g,tanh)
//   lane 32+k(k<21): rowA=21+k (f,sig), rowB=63+k (o,sig)
// One __syncthreads per step; part[] double-buffered with compile-time parity.
// ---------------------------------------------------------------------------
#define RL(h_, l_) __int_as_float(__builtin_amdgcn_readlane(__float_as_int(h_), 32 + (l_)))

#define BCAST_H(h_)                                                        \
    hs_0  = RL(h_, 0);  hs_1  = RL(h_, 1);  hs_2  = RL(h_, 2);             \
    hs_3  = RL(h_, 3);  hs_4  = RL(h_, 4);  hs_5  = RL(h_, 5);             \
    hs_6  = RL(h_, 6);  hs_7  = RL(h_, 7);  hs_8  = RL(h_, 8);             \
    hs_9  = RL(h_, 9);  hs_10 = RL(h_, 10); hs_11 = RL(h_, 11);            \
    hs_12 = RL(h_, 12); hs_13 = RL(h_, 13); hs_14 = RL(h_, 14);            \
    hs_15 = RL(h_, 15); hs_16 = RL(h_, 16); hs_17 = RL(h_, 17);            \
    hs_18 = RL(h_, 18); hs_19 = RL(h_, 19); hs_20 = RL(h_, 20);

// computes gates from zA_,zB_, updates c, defines hW, broadcasts to hs_*
#define STEP_CORE(zA_, zB_)                                                \
        float a0 = (zA_), a1 = 0.0f, a2 = 0.0f;                            \
        float b0 = (zB_), b1 = 0.0f, b2 = 0.0f;                            \
        a0 = __builtin_fmaf(wa_0,  hs_0,  a0);                             \
        b0 = __builtin_fmaf(wb_0,  hs_0,  b0);                             \
        a0 = __builtin_fmaf(wa_1,  hs_1,  a0);                             \
        b0 = __builtin_fmaf(wb_1,  hs_1,  b0);                             \
        a0 = __builtin_fmaf(wa_2,  hs_2,  a0);                             \
        b0 = __builtin_fmaf(wb_2,  hs_2,  b0);                             \
        a0 = __builtin_fmaf(wa_3,  hs_3,  a0);                             \
        b0 = __builtin_fmaf(wb_3,  hs_3,  b0);                             \
        a0 = __builtin_fmaf(wa_4,  hs_4,  a0);                             \
        b0 = __builtin_fmaf(wb_4,  hs_4,  b0);                             \
        a0 = __builtin_fmaf(wa_5,  hs_5,  a0);                             \
        b0 = __builtin_fmaf(wb_5,  hs_5,  b0);                             \
        a0 = __builtin_fmaf(wa_6,  hs_6,  a0);                             \
        b0 = __builtin_fmaf(wb_6,  hs_6,  b0);                             \
        a1 = __builtin_fmaf(wa_7,  hs_7,  a1);                             \
        b1 = __builtin_fmaf(wb_7,  hs_7,  b1);                             \
        a1 = __builtin_fmaf(wa_8,  hs_8,  a1);                             \
        b1 = __builtin_fmaf(wb_8,  hs_8,  b1);                             \
        a1 = __builtin_fmaf(wa_9,  hs_9,  a1);                             \
        b1 = __builtin_fmaf(wb_9,  hs_9,  b1);                             \
        a1 = __builtin_fmaf(wa_10, hs_10, a1);                             \
        b1 = __builtin_fmaf(wb_10, hs_10, b1);                             \
        a1 = __builtin_fmaf(wa_11, hs_11, a1);                             \
        b1 = __builtin_fmaf(wb_11, hs_11, b1);                             \
        a1 = __builtin_fmaf(wa_12, hs_12, a1);                             \
        b1 = __builtin_fmaf(wb_12, hs_12, b1);                             \
        a1 = __builtin_fmaf(wa_13, hs_13, a1);                             \
        b1 = __builtin_fmaf(wb_13, hs_13, b1);                             \
        a2 = __builtin_fmaf(wa_14, hs_14, a2);                             \
        b2 = __builtin_fmaf(wb_14, hs_14, b2);                             \
        a2 = __builtin_fmaf(wa_15, hs_15, a2);                             \
        b2 = __builtin_fmaf(wb_15, hs_15, b2);                             \
        a2 = __builtin_fmaf(wa_16, hs_16, a2);                             \
        b2 = __builtin_fmaf(wb_16, hs_16, b2);                             \
        a2 = __builtin_fmaf(wa_17, hs_17, a2);                             \
        b2 = __builtin_fmaf(wb_17, hs_17, b2);                             \
        a2 = __builtin_fmaf(wa_18, hs_18, a2);                             \
        b2 = __builtin_fmaf(wb_18, hs_18, b2);                             \
        a2 = __builtin_fmaf(wa_19, hs_19, a2);                             \
        b2 = __builtin_fmaf(wb_19, hs_19, b2);                             \
        a2 = __builtin_fmaf(wa_20, hs_20, a2);                             \
        b2 = __builtin_fmaf(wb_20, hs_20, b2);                             \
        float accA = (a0 + a1) + a2;                                       \
        float accB = (b0 + b1) + b2;                                       \
        float vA = sigm(accA);                                             \
        float vB = __builtin_fmaf(mBc, sigm(sB * accB), aB);               \
        float p_  = vA * vB;                                               \
        float pSw = __shfl_xor(p_, 32);                                    \
        c = __builtin_fmaf(vA, c, pSw);                                    \
        float th_ = tanh_stable(c);                                        \
        float hW  = vB * th_;                                              \
        BCAST_H(hW)

// wave0/1: folded input projection for LSTM3, written to LDS partials
#define PROJ(slot_)                                                        \
    {                                                                      \
        float pa0 = 0, pa1 = 0, pa2 = 0, pb0 = 0, pb1 = 0, pb2 = 0;        \
        pa0 = __builtin_fmaf(ma_0,  hs_0,  pa0);                           \
        pb0 = __builtin_fmaf(mb_0,  hs_0,  pb0);                           \
        pa0 = __builtin_fmaf(ma_1,  hs_1,  pa0);                           \
        pb0 = __builtin_fmaf(mb_1,  hs_1,  pb0);                           \
        pa0 = __builtin_fmaf(ma_2,  hs_2,  pa0);                           \
        pb0 = __builtin_fmaf(mb_2,  hs_2,  pb0);                           \
        pa0 = __builtin_fmaf(ma_3,  hs_3,  pa0);                           \
        pb0 = __builtin_fmaf(mb_3,  hs_3,  pb0);                           \
        pa0 = __builtin_fmaf(ma_4,  hs_4,  pa0);                           \
        pb0 = __builtin_fmaf(mb_4,  hs_4,  pb0);                           \
        pa0 = __builtin_fmaf(ma_5,  hs_5,  pa0);                           \
        pb0 = __builtin_fmaf(mb_5,  hs_5,  pb0);                           \
        pa0 = __builtin_fmaf(ma_6,  hs_6,  pa0);                           \
        pb0 = __builtin_fmaf(mb_6,  hs_6,  pb0);                           \
        pa1 = __builtin_fmaf(ma_7,  hs_7,  pa1);                           \
        pb1 = __builtin_fmaf(mb_7,  hs_7,  pb1);                           \
        pa1 = __builtin_fmaf(ma_8,  hs_8,  pa1);                           \
        pb1 = __builtin_fmaf(mb_8,  hs_8,  pb1);                           \
        pa1 = __builtin_fmaf(ma_9,  hs_9,  pa1);                           \
        pb1 = __builtin_fmaf(mb_9,  hs_9,  pb1);                           \
        pa1 = __builtin_fmaf(ma_10, hs_10, pa1);                           \
        pb1 = __builtin_fmaf(mb_10, hs_10, pb1);                           \
        pa1 = __builtin_fmaf(ma_11, hs_11, pa1);                           \
        pb1 = __builtin_fmaf(mb_11, hs_11, pb1);                           \
        pa1 = __builtin_fmaf(ma_12, hs_12, pa1);                           \
        pb1 = __builtin_fmaf(mb_12, hs_12, pb1);                           \
        pa1 = __builtin_fmaf(ma_13, hs_13, pa1);                           \
        pb1 = __builtin_fmaf(mb_13, hs_13, pb1);                           \
        pa2 = __builtin_fmaf(ma_14, hs_14, pa2);                           \
        pb2 = __builtin_fmaf(mb_14, hs_14, pb2);                           \
        pa2 = __builtin_fmaf(ma_15, hs_15, pa2);                           \
        pb2 = __builtin_fmaf(mb_15, hs_15, pb2);                           \
        pa2 = __builtin_fmaf(ma_16, hs_16, pa2);                           \
        pb2 = __builtin_fmaf(mb_16, hs_16, pb2);                           \
        pa2 = __builtin_fmaf(ma_17, hs_17, pa2);                           \
        pb2 = __builtin_fmaf(mb_17, hs_17, pb2);                           \
        pa2 = __builtin_fmaf(ma_18, hs_18, pa2);                           \
        pb2 = __builtin_fmaf(mb_18, hs_18, pb2);                           \
        pa2 = __builtin_fmaf(ma_19, hs_19, pa2);                           \
        pb2 = __builtin_fmaf(mb_19, hs_19, pb2);                           \
        pa2 = __builtin_fmaf(ma_20, hs_20, pa2);                           \
        pb2 = __builtin_fmaf(mb_20, hs_20, pb2);                           \
        if (act) {                                                         \
            part[wid][slot_][rowA] = (pa0 + pa1) + pa2;                    \
            part[wid][slot_][rowB] = (pb0 + pb1) + pb2;                    \
        }                                                                  \
    }

// one pipeline step: waves 0/1 do step t01=4g+ph, wave2 does t01-1.
#define PHASE(ph_, e_)                                                     \
    {                                                                      \
        const int t01 = g * 4 + (ph_);                                     \
        if (wid < 2) {                                                     \
            if (t01 < T_LEN) {                                             \
                STEP_CORE(cA.e_, cB.e_)                                    \
                PROJ((ph_) & 1)                                            \
            }                                                              \
        } else {                                                           \
            const int t2 = t01 - 1;                                        \
            if ((unsigned)t2 < (unsigned)T_LEN) {                          \
                float zA = b3A + part[0][((ph_) + 1) & 1][rowA]            \
                               + part[1][((ph_) + 1) & 1][rowA];           \
                float zB = b3B + part[0][((ph_) + 1) & 1][rowB]            \
                               + part[1][((ph_) + 1) & 1][rowB];           \
                STEP_CORE(zA, zB)                                          \
                if (hi && act) h3out[t2 * HDIM + k] = hW;                  \
            }                                                              \
        }                                                                  \
        __syncthreads();                                                   \
    }

#define LDG4(p_) (*reinterpret_cast<const float4*>(p_))

__global__ __launch_bounds__(192, 1)
void fused_scan_kernel(const float* __restrict__ zxG1, const float* __restrict__ Whh1,
                       const float* __restrict__ M1,
                       const float* __restrict__ zxG2, const float* __restrict__ Whh2,
                       const float* __restrict__ M2,
                       const float* __restrict__ Whh3, const float* __restrict__ b3p,
                       float* __restrict__ h3out)
{
    __shared__ float part[2][2][GDIM];   // [which LSTM][slot][gate row]

    const int wid  = threadIdx.x >> 6;   // 0,1,2
    const int lane = threadIdx.x & 63;
    const int k = lane & 31;
    const bool hi = lane >= 32;
    const bool act = k < HDIM;
    const int kk = act ? k : 0;

    const int rowA = hi ? (HDIM + kk)     : kk;              // f : i  (sigmoid)
    const int rowB = hi ? (3 * HDIM + kk) : (2 * HDIM + kk); // o : g
    const float sB  = hi ? 1.0f : 2.0f;  // lo: tanh via 2*sigm(2x)-1 ; hi: sigm
    const float mBc = hi ? 1.0f : 2.0f;
    const float aB  = hi ? 0.0f : -1.0f;

    const float* Whh = (wid == 0) ? Whh1 : (wid == 1) ? Whh2 : Whh3;
    const float* zxG = (wid == 1) ? zxG2 : zxG1;             // dummy for wid2
    const float* Mm  = (wid == 0) ? M1 : (wid == 1) ? M2 : Whh3; // dummy wid2

    const float* WA = Whh + rowA * HDIM;
    const float* WB = Whh + rowB * HDIM;
    const float* MA = Mm  + rowA * HDIM;
    const float* MB = Mm  + rowB * HDIM;

    // recurrent weights: 42 named scalars
    float wa_0  = WA[0],  wa_1  = WA[1],  wa_2  = WA[2],  wa_3  = WA[3];
    float wa_4  = WA[4],  wa_5  = WA[5],  wa_6  = WA[6],  wa_7  = WA[7];
    float wa_8  = WA[8],  wa_9  = WA[9],  wa_10 = WA[10], wa_11 = WA[11];
    float wa_12 = WA[12], wa_13 = WA[13], wa_14 = WA[14], wa_15 = WA[15];
    float wa_16 = WA[16], wa_17 = WA[17], wa_18 = WA[18], wa_19 = WA[19];
    float wa_20 = WA[20];
    float wb_0  = WB[0],  wb_1  = WB[1],  wb_2  = WB[2],  wb_3  = WB[3];
    float wb_4  = WB[4],  wb_5  = WB[5],  wb_6  = WB[6],  wb_7  = WB[7];
    float wb_8  = WB[8],  wb_9  = WB[9],  wb_10 = WB[10], wb_11 = WB[11];
    float wb_12 = WB[12], wb_13 = WB[13], wb_14 = WB[14], wb_15 = WB[15];
    float wb_16 = WB[16], wb_17 = WB[17], wb_18 = WB[18], wb_19 = WB[19];
    float wb_20 = WB[20];

    // projection weights (waves 0/1; harmless garbage for wave2)
    float ma_0  = MA[0],  ma_1  = MA[1],  ma_2  = MA[2],  ma_3  = MA[3];
    float ma_4  = MA[4],  ma_5  = MA[5],  ma_6  = MA[6],  ma_7  = MA[7];
    float ma_8  = MA[8],  ma_9  = MA[9],  ma_10 = MA[10], ma_11 = MA[11];
    float ma_12 = MA[12], ma_13 = MA[13], ma_14 = MA[14], ma_15 = MA[15];
    float ma_16 = MA[16], ma_17 = MA[17], ma_18 = MA[18], ma_19 = MA[19];
    float ma_20 = MA[20];
    float mb_0  = MB[0],  mb_1  = MB[1],  mb_2  = MB[2],  mb_3  = MB[3];
    float mb_4  = MB[4],  mb_5  = MB[5],  mb_6  = MB[6],  mb_7  = MB[7];
    float mb_8  = MB[8],  mb_9  = MB[9],  mb_10 = MB[10], mb_11 = MB[11];
    float mb_12 = MB[12], mb_13 = MB[13], mb_14 = MB[14], mb_15 = MB[15];
    float mb_16 = MB[16], mb_17 = MB[17], mb_18 = MB[18], mb_19 = MB[19];
    float mb_20 = MB[20];

    const float b3A = b3p[rowA];
    const float b3B = b3p[rowB];

    // h state (wave-uniform after readlane) + cell state
    float hs_0 = 0, hs_1 = 0, hs_2 = 0, hs_3 = 0, hs_4 = 0, hs_5 = 0, hs_6 = 0;
    float hs_7 = 0, hs_8 = 0, hs_9 = 0, hs_10 = 0, hs_11 = 0, hs_12 = 0;
    float hs_13 = 0, hs_14 = 0, hs_15 = 0, hs_16 = 0, hs_17 = 0, hs_18 = 0;
    float hs_19 = 0, hs_20 = 0;
    float c = 0.0f;

    // zx stream (waves 0/1): current group + next group, prefetch g+2
    const float* baseA = zxG + rowA * 4;
    const float* baseB = zxG + rowB * 4;
    float4 cA, cB, nA, nB;
    if (wid < 2) {
        cA = LDG4(baseA);           cB = LDG4(baseB);
        nA = LDG4(baseA + GSTRIDE); nB = LDG4(baseB + GSTRIDE);
    }

    __syncthreads();   // part[] not yet valid; first wave2 step is skipped anyway

#pragma unroll 1
    for (int g = 0; g < NIT; ++g) {
        float4 fA, fB;
        if (wid < 2) {
            const float* pA = baseA + (size_t)(g + 2) * GSTRIDE; // overrun ok (mapped ws)
            const float* pB = baseB + (size_t)(g + 2) * GSTRIDE;
            fA = LDG4(pA); fB = LDG4(pB);
        }
        PHASE(0, x)
        PHASE(1, y)
        PHASE(2, z)
        PHASE(3, w)
        if (wid < 2) { cA = nA; cB = nB; nA = fA; nB = fB; }
    }
}

// ---------------------------------------------------------------------------
// K4: final linear: out[t] = h3[t] @ W3.T + bl3   (W3: [2,21])
// ---------------------------------------------------------------------------
__global__ void out_kernel(const float* __restrict__ h3, const float* __restrict__ W3,
                           const float* __restrict__ bl3, float* __restrict__ out)
{
    int t = blockIdx.x * blockDim.x + threadIdx.x;
    if (t >= T_LEN) return;
    float s0 = bl3[0], s1 = bl3[1];
#pragma unroll
    for (int kq = 0; kq < HDIM; ++kq) {
        float h = h3[t * HDIM + kq];
        s0 = __builtin_fmaf(W3[kq], h, s0);
        s1 = __builtin_fmaf(W3[HDIM + kq], h, s1);
    }
    out[t * 2 + 0] = s0;
    out[t * 2 + 1] = s1;
}

extern "C" void kernel_launch(void* const* d_in, const int* in_sizes, int n_in,
                              void* d_out, int out_size, void* d_ws, size_t ws_size,
                              hipStream_t stream) {
    const float* src  = (const float*)d_in[0];
    const float* Wih1 = (const float*)d_in[1];
    const float* Whh1 = (const float*)d_in[2];
    const float* b1   = (const float*)d_in[3];
    const float* W1   = (const float*)d_in[4];
    const float* bl1  = (const float*)d_in[5];
    const float* Wih2 = (const float*)d_in[6];
    const float* Whh2 = (const float*)d_in[7];
    const float* b2   = (const float*)d_in[8];
    const float* W2   = (const float*)d_in[9];
    const float* bl2  = (const float*)d_in[10];
    const float* Wih3 = (const float*)d_in[11];
    const float* Whh3 = (const float*)d_in[12];
    const float* b3   = (const float*)d_in[13];
    const float* W3   = (const float*)d_in[14];
    const float* bl3  = (const float*)d_in[15];
    float* out = (float*)d_out;

    float* ws   = (float*)d_ws;
    float* zxG1 = ws;
    float* zxG2 = zxG1 + (size_t)T_LEN * GDIM;
    float* h3   = zxG2 + (size_t)T_LEN * GDIM;   // also absorbs zxG2's 2-group prefetch overrun
    float* M1   = h3   + (size_t)T_LEN * HDIM;
    float* M2   = M1   + GDIM * HDIM;
    float* b3p  = M2   + GDIM * HDIM;

    zx12_kernel<<<(T_LEN * GDIM + 255) / 256, 256, 0, stream>>>(
        src, Wih1, b1, Wih2, b2, zxG1, zxG2);
    fold_kernel<<<(GDIM * HDIM + 255) / 256, 256, 0, stream>>>(
        Wih3, W1, bl1, W2, bl2, b3, M1, M2, b3p);
    fused_scan_kernel<<<1, 192, 0, stream>>>(
        zxG1, Whh1, M1, zxG2, Whh2, M2, Whh3, b3p, h3);
    out_kernel<<<(T_LEN + 255) / 256, 256, 0, stream>>>(h3, W3, bl3, out);
}

// Round 11
// 3332.510 us; speedup vs baseline: 1.3250x; 1.3250x over previous
//
#include <hip/hip_runtime.h>
#include <hip/hip_bf16.h>

// Problem constants (from reference): T=8192 steps, batch=1, H=21 hidden.
#define T_LEN 8192
#define HDIM  21
#define GDIM  84           // 4*H gate rows
#define NGRP  (T_LEN / 4)  // 2048 groups of 4 timesteps
#define GSTRIDE (GDIM * 4) // 336 floats per group block
#define CHUNK 16           // steps per fused superstep (4 groups)
#define NCHUNK (T_LEN / CHUNK) // 512

// Workspace layout (floats):
//  zxG1[2048*336] zxG2[2048*336]  (GROUPED: [t/4][row][4])
//  h3[8192*21] M1[84*21] M2[84*21] b3p[84]
// All scan loads are clamped in-bounds (no overrun this round).

__device__ __forceinline__ float sigm(float x) {
    return 1.0f / (1.0f + __expf(-x));   // stable both directions
}
__device__ __forceinline__ float tanh_stable(float x) {
    float e = __expf(2.0f * x);          // +inf -> 1, -inf -> -1, no inf/inf
    return 1.0f - 2.0f / (e + 1.0f);
}

// ---------------------------------------------------------------------------
// K1: parallel input projections, GROUPED output zxG[g][j][q] (coalesced).
// ---------------------------------------------------------------------------
__global__ void zx12_kernel(const float* __restrict__ src,
                            const float* __restrict__ Wih1, const float* __restrict__ b1,
                            const float* __restrict__ Wih2, const float* __restrict__ b2,
                            float* __restrict__ zxG1, float* __restrict__ zxG2)
{
    int n = blockIdx.x * blockDim.x + threadIdx.x;
    if (n >= T_LEN * GDIM) return;
    unsigned g = (unsigned)n / GSTRIDE;
    unsigned r = (unsigned)n - g * GSTRIDE;
    unsigned j = r >> 2;
    unsigned t = (g << 2) | (r & 3);
    float4 s = *reinterpret_cast<const float4*>(src + 4 * t);
    float z1 = b1[j];
    z1 = __builtin_fmaf(Wih1[j * 3 + 0], s.x, z1);
    z1 = __builtin_fmaf(Wih1[j * 3 + 1], s.z, z1);
    z1 = __builtin_fmaf(Wih1[j * 3 + 2], s.w, z1);
    float z2 = b2[j];
    z2 = __builtin_fmaf(Wih2[j * 3 + 0], s.y, z2);
    z2 = __builtin_fmaf(Wih2[j * 3 + 1], s.z, z2);
    z2 = __builtin_fmaf(Wih2[j * 3 + 2], s.w, z2);
    zxG1[n] = z1;
    zxG2[n] = z2;
}

// ---------------------------------------------------------------------------
// K2: fold linear layers into LSTM3's input projection.
// ---------------------------------------------------------------------------
__global__ void fold_kernel(const float* __restrict__ Wih3,
                            const float* __restrict__ W1, const float* __restrict__ bl1,
                            const float* __restrict__ W2, const float* __restrict__ bl2,
                            const float* __restrict__ b3,
                            float* __restrict__ M1, float* __restrict__ M2,
                            float* __restrict__ b3p)
{
    int idx = blockIdx.x * blockDim.x + threadIdx.x;
    if (idx < GDIM * HDIM) {
        int j = idx / HDIM, k = idx - j * HDIM;
        M1[idx] = Wih3[j * 50 + 0] * W1[k];
        float s = 0.0f;
        for (int m = 0; m < 49; ++m)
            s = __builtin_fmaf(Wih3[j * 50 + 1 + m], W2[m * HDIM + k], s);
        M2[idx] = s;
    }
    if (idx < GDIM) {
        float s = b3[idx] + Wih3[idx * 50 + 0] * bl1[0];
        for (int m = 0; m < 49; ++m)
            s = __builtin_fmaf(Wih3[idx * 50 + 1 + m], bl2[m], s);
        b3p[idx] = s;
    }
}

// ---------------------------------------------------------------------------
// K3: CHUNKED fused 3-LSTM scan. One block, 3 waves:
//   wave0 = LSTM1, wave1 = LSTM2: compute CHUNK=16 steps, write folded
//           projections (M*h) into LDS part[wid][buf][s][row].
//   wave2 = LSTM3: one chunk behind, assembles zx3 from LDS partials.
// ONE __syncthreads per 16 steps (amortizes the barrier vmcnt/lgkm drain that
// made per-step sync cost ~700cy in R10). zx loads prefetched a full chunk
// ahead so the barrier drain is free.
// ---------------------------------------------------------------------------
#define RL(h_, l_) __int_as_float(__builtin_amdgcn_readlane(__float_as_int(h_), 32 + (l_)))

#define BCAST_H(h_)                                                        \
    hs_0  = RL(h_, 0);  hs_1  = RL(h_, 1);  hs_2  = RL(h_, 2);             \
    hs_3  = RL(h_, 3);  hs_4  = RL(h_, 4);  hs_5  = RL(h_, 5);             \
    hs_6  = RL(h_, 6);  hs_7  = RL(h_, 7);  hs_8  = RL(h_, 8);             \
    hs_9  = RL(h_, 9);  hs_10 = RL(h_, 10); hs_11 = RL(h_, 11);            \
    hs_12 = RL(h_, 12); hs_13 = RL(h_, 13); hs_14 = RL(h_, 14);            \
    hs_15 = RL(h_, 15); hs_16 = RL(h_, 16); hs_17 = RL(h_, 17);            \
    hs_18 = RL(h_, 18); hs_19 = RL(h_, 19); hs_20 = RL(h_, 20);

// gates from zA_,zB_; updates c; defines hW; broadcasts to hs_*
#define STEP_CORE(zA_, zB_)                                                \
        float a0 = (zA_), a1 = 0.0f, a2 = 0.0f;                            \
        float b0 = (zB_), b1 = 0.0f, b2 = 0.0f;                            \
        a0 = __builtin_fmaf(wa_0,  hs_0,  a0);                             \
        b0 = __builtin_fmaf(wb_0,  hs_0,  b0);                             \
        a0 = __builtin_fmaf(wa_1,  hs_1,  a0);                             \
        b0 = __builtin_fmaf(wb_1,  hs_1,  b0);                             \
        a0 = __builtin_fmaf(wa_2,  hs_2,  a0);                             \
        b0 = __builtin_fmaf(wb_2,  hs_2,  b0);                             \
        a0 = __builtin_fmaf(wa_3,  hs_3,  a0);                             \
        b0 = __builtin_fmaf(wb_3,  hs_3,  b0);                             \
        a0 = __builtin_fmaf(wa_4,  hs_4,  a0);                             \
        b0 = __builtin_fmaf(wb_4,  hs_4,  b0);                             \
        a0 = __builtin_fmaf(wa_5,  hs_5,  a0);                             \
        b0 = __builtin_fmaf(wb_5,  hs_5,  b0);                             \
        a0 = __builtin_fmaf(wa_6,  hs_6,  a0);                             \
        b0 = __builtin_fmaf(wb_6,  hs_6,  b0);                             \
        a1 = __builtin_fmaf(wa_7,  hs_7,  a1);                             \
        b1 = __builtin_fmaf(wb_7,  hs_7,  b1);                             \
        a1 = __builtin_fmaf(wa_8,  hs_8,  a1);                             \
        b1 = __builtin_fmaf(wb_8,  hs_8,  b1);                             \
        a1 = __builtin_fmaf(wa_9,  hs_9,  a1);                             \
        b1 = __builtin_fmaf(wb_9,  hs_9,  b1);                             \
        a1 = __builtin_fmaf(wa_10, hs_10, a1);                             \
        b1 = __builtin_fmaf(wb_10, hs_10, b1);                             \
        a1 = __builtin_fmaf(wa_11, hs_11, a1);                             \
        b1 = __builtin_fmaf(wb_11, hs_11, b1);                             \
        a1 = __builtin_fmaf(wa_12, hs_12, a1);                             \
        b1 = __builtin_fmaf(wb_12, hs_12, b1);                             \
        a1 = __builtin_fmaf(wa_13, hs_13, a1);                             \
        b1 = __builtin_fmaf(wb_13, hs_13, b1);                             \
        a2 = __builtin_fmaf(wa_14, hs_14, a2);                             \
        b2 = __builtin_fmaf(wb_14, hs_14, b2);                             \
        a2 = __builtin_fmaf(wa_15, hs_15, a2);                             \
        b2 = __builtin_fmaf(wb_15, hs_15, b2);                             \
        a2 = __builtin_fmaf(wa_16, hs_16, a2);                             \
        b2 = __builtin_fmaf(wb_16, hs_16, b2);                             \
        a2 = __builtin_fmaf(wa_17, hs_17, a2);                             \
        b2 = __builtin_fmaf(wb_17, hs_17, b2);                             \
        a2 = __builtin_fmaf(wa_18, hs_18, a2);                             \
        b2 = __builtin_fmaf(wb_18, hs_18, b2);                             \
        a2 = __builtin_fmaf(wa_19, hs_19, a2);                             \
        b2 = __builtin_fmaf(wb_19, hs_19, b2);                             \
        a2 = __builtin_fmaf(wa_20, hs_20, a2);                             \
        b2 = __builtin_fmaf(wb_20, hs_20, b2);                             \
        float accA = (a0 + a1) + a2;                                       \
        float accB = (b0 + b1) + b2;                                       \
        float vA = sigm(accA);                                             \
        float vB = __builtin_fmaf(mBc, sigm(sB * accB), aB);               \
        float p_  = vA * vB;                                               \
        float pSw = __shfl_xor(p_, 32);                                    \
        c = __builtin_fmaf(vA, c, pSw);                                    \
        float th_ = tanh_stable(c);                                        \
        float hW  = vB * th_;                                              \
        BCAST_H(hW)

// waves 0/1: one step + folded projection into LDS at slot s_
#define W01_STEP(s_, zA_, zB_)                                             \
    {                                                                      \
        STEP_CORE(zA_, zB_)                                                \
        float pa0 = 0, pa1 = 0, pa2 = 0, pb0 = 0, pb1 = 0, pb2 = 0;        \
        pa0 = __builtin_fmaf(ma_0,  hs_0,  pa0);                           \
        pb0 = __builtin_fmaf(mb_0,  hs_0,  pb0);                           \
        pa0 = __builtin_fmaf(ma_1,  hs_1,  pa0);                           \
        pb0 = __builtin_fmaf(mb_1,  hs_1,  pb0);                           \
        pa0 = __builtin_fmaf(ma_2,  hs_2,  pa0);                           \
        pb0 = __builtin_fmaf(mb_2,  hs_2,  pb0);                           \
        pa0 = __builtin_fmaf(ma_3,  hs_3,  pa0);                           \
        pb0 = __builtin_fmaf(mb_3,  hs_3,  pb0);                           \
        pa0 = __builtin_fmaf(ma_4,  hs_4,  pa0);                           \
        pb0 = __builtin_fmaf(mb_4,  hs_4,  pb0);                           \
        pa0 = __builtin_fmaf(ma_5,  hs_5,  pa0);                           \
        pb0 = __builtin_fmaf(mb_5,  hs_5,  pb0);                           \
        pa0 = __builtin_fmaf(ma_6,  hs_6,  pa0);                           \
        pb0 = __builtin_fmaf(mb_6,  hs_6,  pb0);                           \
        pa1 = __builtin_fmaf(ma_7,  hs_7,  pa1);                           \
        pb1 = __builtin_fmaf(mb_7,  hs_7,  pb1);                           \
        pa1 = __builtin_fmaf(ma_8,  hs_8,  pa1);                           \
        pb1 = __builtin_fmaf(mb_8,  hs_8,  pb1);                           \
        pa1 = __builtin_fmaf(ma_9,  hs_9,  pa1);                           \
        pb1 = __builtin_fmaf(mb_9,  hs_9,  pb1);                           \
        pa1 = __builtin_fmaf(ma_10, hs_10, pa1);                           \
        pb1 = __builtin_fmaf(mb_10, hs_10, pb1);                           \
        pa1 = __builtin_fmaf(ma_11, hs_11, pa1);                           \
        pb1 = __builtin_fmaf(mb_11, hs_11, pb1);                           \
        pa1 = __builtin_fmaf(ma_12, hs_12, pa1);                           \
        pb1 = __builtin_fmaf(mb_12, hs_12, pb1);                           \
        pa1 = __builtin_fmaf(ma_13, hs_13, pa1);                           \
        pb1 = __builtin_fmaf(mb_13, hs_13, pb1);                           \
        pa2 = __builtin_fmaf(ma_14, hs_14, pa2);                           \
        pb2 = __builtin_fmaf(mb_14, hs_14, pb2);                           \
        pa2 = __builtin_fmaf(ma_15, hs_15, pa2);                           \
        pb2 = __builtin_fmaf(mb_15, hs_15, pb2);                           \
        pa2 = __builtin_fmaf(ma_16, hs_16, pa2);                           \
        pb2 = __builtin_fmaf(mb_16, hs_16, pb2);                           \
        pa2 = __builtin_fmaf(ma_17, hs_17, pa2);                           \
        pb2 = __builtin_fmaf(mb_17, hs_17, pb2);                           \
        pa2 = __builtin_fmaf(ma_18, hs_18, pa2);                           \
        pb2 = __builtin_fmaf(mb_18, hs_18, pb2);                           \
        pa2 = __builtin_fmaf(ma_19, hs_19, pa2);                           \
        pb2 = __builtin_fmaf(mb_19, hs_19, pb2);                           \
        pa2 = __builtin_fmaf(ma_20, hs_20, pa2);                           \
        pb2 = __builtin_fmaf(mb_20, hs_20, pb2);                           \
        if (act) {                                                         \
            pp[(s_) * GDIM + rowA] = (pa0 + pa1) + pa2;                    \
            pp[(s_) * GDIM + rowB] = (pb0 + pb1) + pb2;                    \
        }                                                                  \
    }

// wave2: one LSTM3 step from LDS partials at slot s_
#define W2_STEP(s_)                                                        \
    {                                                                      \
        float zA = b3A + p0[(s_) * GDIM + rowA] + p1[(s_) * GDIM + rowA];  \
        float zB = b3B + p0[(s_) * GDIM + rowB] + p1[(s_) * GDIM + rowB];  \
        STEP_CORE(zA, zB)                                                  \
        if (hi && act) h3out[(tbase + (s_)) * HDIM + k] = hW;              \
    }

#define LDG4(p_) (*reinterpret_cast<const float4*>(p_))

__global__ __launch_bounds__(192, 1)
void fused_scan_kernel(const float* __restrict__ zxG1, const float* __restrict__ Whh1,
                       const float* __restrict__ M1,
                       const float* __restrict__ zxG2, const float* __restrict__ Whh2,
                       const float* __restrict__ M2,
                       const float* __restrict__ Whh3, const float* __restrict__ b3p,
                       float* __restrict__ h3out)
{
    __shared__ float part[2][2][CHUNK][GDIM];   // [lstm][buf][step][row] = 21.5KB

    const int wid  = threadIdx.x >> 6;   // 0,1,2
    const int lane = threadIdx.x & 63;
    const int k = lane & 31;
    const bool hi = lane >= 32;
    const bool act = k < HDIM;
    const int kk = act ? k : 0;

    const int rowA = hi ? (HDIM + kk)     : kk;              // f : i  (sigmoid)
    const int rowB = hi ? (3 * HDIM + kk) : (2 * HDIM + kk); // o : g
    const float sB  = hi ? 1.0f : 2.0f;  // lo: tanh via 2*sigm(2x)-1 ; hi: sigm
    const float mBc = hi ? 1.0f : 2.0f;
    const float aB  = hi ? 0.0f : -1.0f;

    const float* Whh = (wid == 0) ? Whh1 : (wid == 1) ? Whh2 : Whh3;
    const float* zxG = (wid == 1) ? zxG2 : zxG1;                 // dummy for wid2
    const float* Mm  = (wid == 0) ? M1 : (wid == 1) ? M2 : Whh3; // dummy for wid2

    const float* WA = Whh + rowA * HDIM;
    const float* WB = Whh + rowB * HDIM;
    const float* MA = Mm  + rowA * HDIM;
    const float* MB = Mm  + rowB * HDIM;

    // recurrent weights: 42 named scalars
    float wa_0  = WA[0],  wa_1  = WA[1],  wa_2  = WA[2],  wa_3  = WA[3];
    float wa_4  = WA[4],  wa_5  = WA[5],  wa_6  = WA[6],  wa_7  = WA[7];
    float wa_8  = WA[8],  wa_9  = WA[9],  wa_10 = WA[10], wa_11 = WA[11];
    float wa_12 = WA[12], wa_13 = WA[13], wa_14 = WA[14], wa_15 = WA[15];
    float wa_16 = WA[16], wa_17 = WA[17], wa_18 = WA[18], wa_19 = WA[19];
    float wa_20 = WA[20];
    float wb_0  = WB[0],  wb_1  = WB[1],  wb_2  = WB[2],  wb_3  = WB[3];
    float wb_4  = WB[4],  wb_5  = WB[5],  wb_6  = WB[6],  wb_7  = WB[7];
    float wb_8  = WB[8],  wb_9  = WB[9],  wb_10 = WB[10], wb_11 = WB[11];
    float wb_12 = WB[12], wb_13 = WB[13], wb_14 = WB[14], wb_15 = WB[15];
    float wb_16 = WB[16], wb_17 = WB[17], wb_18 = WB[18], wb_19 = WB[19];
    float wb_20 = WB[20];

    // projection weights (waves 0/1; harmless garbage for wave2)
    float ma_0  = MA[0],  ma_1  = MA[1],  ma_2  = MA[2],  ma_3  = MA[3];
    float ma_4  = MA[4],  ma_5  = MA[5],  ma_6  = MA[6],  ma_7  = MA[7];
    float ma_8  = MA[8],  ma_9  = MA[9],  ma_10 = MA[10], ma_11 = MA[11];
    float ma_12 = MA[12], ma_13 = MA[13], ma_14 = MA[14], ma_15 = MA[15];
    float ma_16 = MA[16], ma_17 = MA[17], ma_18 = MA[18], ma_19 = MA[19];
    float ma_20 = MA[20];
    float mb_0  = MB[0],  mb_1  = MB[1],  mb_2  = MB[2],  mb_3  = MB[3];
    float mb_4  = MB[4],  mb_5  = MB[5],  mb_6  = MB[6],  mb_7  = MB[7];
    float mb_8  = MB[8],  mb_9  = MB[9],  mb_10 = MB[10], mb_11 = MB[11];
    float mb_12 = MB[12], mb_13 = MB[13], mb_14 = MB[14], mb_15 = MB[15];
    float mb_16 = MB[16], mb_17 = MB[17], mb_18 = MB[18], mb_19 = MB[19];
    float mb_20 = MB[20];

    const float b3A = b3p[rowA];
    const float b3B = b3p[rowB];

    // state
    float hs_0 = 0, hs_1 = 0, hs_2 = 0, hs_3 = 0, hs_4 = 0, hs_5 = 0, hs_6 = 0;
    float hs_7 = 0, hs_8 = 0, hs_9 = 0, hs_10 = 0, hs_11 = 0, hs_12 = 0;
    float hs_13 = 0, hs_14 = 0, hs_15 = 0, hs_16 = 0, hs_17 = 0, hs_18 = 0;
    float hs_19 = 0, hs_20 = 0;
    float c = 0.0f;

    // zx chunk registers (waves 0/1): current chunk = 4 groups x 2 rows
    const float* baseA = zxG + rowA * 4;
    const float* baseB = zxG + rowB * 4;
    float4 cA0, cA1, cA2, cA3, cB0, cB1, cB2, cB3;
    if (wid < 2) {
        cA0 = LDG4(baseA + 0 * GSTRIDE); cA1 = LDG4(baseA + 1 * GSTRIDE);
        cA2 = LDG4(baseA + 2 * GSTRIDE); cA3 = LDG4(baseA + 3 * GSTRIDE);
        cB0 = LDG4(baseB + 0 * GSTRIDE); cB1 = LDG4(baseB + 1 * GSTRIDE);
        cB2 = LDG4(baseB + 2 * GSTRIDE); cB3 = LDG4(baseB + 3 * GSTRIDE);
    }

#pragma unroll 1
    for (int i = 0; i <= NCHUNK; ++i) {
        // prefetch next chunk (clamped in-bounds; waits land a full chunk later)
        float4 nA0, nA1, nA2, nA3, nB0, nB1, nB2, nB3;
        if (wid < 2) {
            const int gn = (i + 1 < NCHUNK) ? (i + 1) : (NCHUNK - 1);
            const float* pA = baseA + (size_t)gn * 4 * GSTRIDE;
            const float* pB = baseB + (size_t)gn * 4 * GSTRIDE;
            nA0 = LDG4(pA + 0 * GSTRIDE); nA1 = LDG4(pA + 1 * GSTRIDE);
            nA2 = LDG4(pA + 2 * GSTRIDE); nA3 = LDG4(pA + 3 * GSTRIDE);
            nB0 = LDG4(pB + 0 * GSTRIDE); nB1 = LDG4(pB + 1 * GSTRIDE);
            nB2 = LDG4(pB + 2 * GSTRIDE); nB3 = LDG4(pB + 3 * GSTRIDE);

            if (i < NCHUNK) {
                float* pp = &part[wid][i & 1][0][0];
                W01_STEP(0,  cA0.x, cB0.x) W01_STEP(1,  cA0.y, cB0.y)
                W01_STEP(2,  cA0.z, cB0.z) W01_STEP(3,  cA0.w, cB0.w)
                W01_STEP(4,  cA1.x, cB1.x) W01_STEP(5,  cA1.y, cB1.y)
                W01_STEP(6,  cA1.z, cB1.z) W01_STEP(7,  cA1.w, cB1.w)
                W01_STEP(8,  cA2.x, cB2.x) W01_STEP(9,  cA2.y, cB2.y)
                W01_STEP(10, cA2.z, cB2.z) W01_STEP(11, cA2.w, cB2.w)
                W01_STEP(12, cA3.x, cB3.x) W01_STEP(13, cA3.y, cB3.y)
                W01_STEP(14, cA3.z, cB3.z) W01_STEP(15, cA3.w, cB3.w)
            }
        } else if (i >= 1) {
            const int buf = (i - 1) & 1;
            const int tbase = (i - 1) * CHUNK;
            const float* p0 = &part[0][buf][0][0];
            const float* p1 = &part[1][buf][0][0];
            W2_STEP(0)  W2_STEP(1)  W2_STEP(2)  W2_STEP(3)
            W2_STEP(4)  W2_STEP(5)  W2_STEP(6)  W2_STEP(7)
            W2_STEP(8)  W2_STEP(9)  W2_STEP(10) W2_STEP(11)
            W2_STEP(12) W2_STEP(13) W2_STEP(14) W2_STEP(15)
        }
        __syncthreads();
        if (wid < 2) {
            cA0 = nA0; cA1 = nA1; cA2 = nA2; cA3 = nA3;
            cB0 = nB0; cB1 = nB1; cB2 = nB2; cB3 = nB3;
        }
    }
}

// ---------------------------------------------------------------------------
// K4: final linear: out[t] = h3[t] @ W3.T + bl3   (W3: [2,21])
// ---------------------------------------------------------------------------
__global__ void out_kernel(const float* __restrict__ h3, const float* __restrict__ W3,
                           const float* __restrict__ bl3, float* __restrict__ out)
{
    int t = blockIdx.x * blockDim.x + threadIdx.x;
    if (t >= T_LEN) return;
    float s0 = bl3[0], s1 = bl3[1];
#pragma unroll
    for (int kq = 0; kq < HDIM; ++kq) {
        float h = h3[t * HDIM + kq];
        s0 = __builtin_fmaf(W3[kq], h, s0);
        s1 = __builtin_fmaf(W3[HDIM + kq], h, s1);
    }
    out[t * 2 + 0] = s0;
    out[t * 2 + 1] = s1;
}

extern "C" void kernel_launch(void* const* d_in, const int* in_sizes, int n_in,
                              void* d_out, int out_size, void* d_ws, size_t ws_size,
                              hipStream_t stream) {
    const float* src  = (const float*)d_in[0];
    const float* Wih1 = (const float*)d_in[1];
    const float* Whh1 = (const float*)d_in[2];
    const float* b1   = (const float*)d_in[3];
    const float* W1   = (const float*)d_in[4];
    const float* bl1  = (const float*)d_in[5];
    const float* Wih2 = (const float*)d_in[6];
    const float* Whh2 = (const float*)d_in[7];
    const float* b2   = (const float*)d_in[8];
    const float* W2   = (const float*)d_in[9];
    const float* bl2  = (const float*)d_in[10];
    const float* Wih3 = (const float*)d_in[11];
    const float* Whh3 = (const float*)d_in[12];
    const float* b3   = (const float*)d_in[13];
    const float* W3   = (const float*)d_in[14];
    const float* bl3  = (const float*)d_in[15];
    float* out = (float*)d_out;

    float* ws   = (float*)d_ws;
    float* zxG1 = ws;
    float* zxG2 = zxG1 + (size_t)T_LEN * GDIM;
    float* h3   = zxG2 + (size_t)T_LEN * GDIM;
    float* M1   = h3   + (size_t)T_LEN * HDIM;
    float* M2   = M1   + GDIM * HDIM;
    float* b3p  = M2   + GDIM * HDIM;

    zx12_kernel<<<(T_LEN * GDIM + 255) / 256, 256, 0, stream>>>(
        src, Wih1, b1, Wih2, b2, zxG1, zxG2);
    fold_kernel<<<(GDIM * HDIM + 255) / 256, 256, 0, stream>>>(
        Wih3, W1, bl1, W2, bl2, b3, M1, M2, b3p);
    fused_scan_kernel<<<1, 192, 0, stream>>>(
        zxG1, Whh1, M1, zxG2, Whh2, M2, Whh3, b3p, h3);
    out_kernel<<<(T_LEN + 255) / 256, 256, 0, stream>>>(h3, W3, bl3, out);
}

// Round 12
// 2898.676 us; speedup vs baseline: 1.5233x; 1.1497x over previous
//
#include <hip/hip_runtime.h>
#include <hip/hip_bf16.h>

// Problem constants (from reference): T=8192 steps, batch=1, H=21 hidden.
#define T_LEN 8192
#define HDIM  21
#define GDIM  84           // 4*H gate rows
#define NGRP  (T_LEN / 4)  // 2048 groups of 4 timesteps
#define GSTRIDE (GDIM * 4) // 336 floats per group block
#define CHUNK 16           // steps per fused superstep (4 groups)
#define NCHUNK (T_LEN / CHUNK) // 512

// Workspace layout (floats):
//  zxG1[2048*336] zxG2[2048*336]  (GROUPED: [t/4][row][4])
//  h3[8192*21] M1[84*21] M2[84*21] b3p[84]
// All scan loads are clamped in-bounds.

__device__ __forceinline__ float rcp_fast(float x) {
    return __builtin_amdgcn_rcpf(x);     // v_rcp_f32, ~1ulp; rcp(inf)=0, rcp(1)=1
}
__device__ __forceinline__ float sigm(float x) {
    return rcp_fast(1.0f + __expf(-x));  // stable both directions
}
__device__ __forceinline__ float tanh_stable(float x) {
    float e = __expf(2.0f * x);          // +inf -> 1, -inf -> -1, no inf/inf
    return __builtin_fmaf(-2.0f, rcp_fast(e + 1.0f), 1.0f);
}

// ---------------------------------------------------------------------------
// K1: parallel input projections, GROUPED output zxG[g][j][q] (coalesced).
// ---------------------------------------------------------------------------
__global__ void zx12_kernel(const float* __restrict__ src,
                            const float* __restrict__ Wih1, const float* __restrict__ b1,
                            const float* __restrict__ Wih2, const float* __restrict__ b2,
                            float* __restrict__ zxG1, float* __restrict__ zxG2)
{
    int n = blockIdx.x * blockDim.x + threadIdx.x;
    if (n >= T_LEN * GDIM) return;
    unsigned g = (unsigned)n / GSTRIDE;
    unsigned r = (unsigned)n - g * GSTRIDE;
    unsigned j = r >> 2;
    unsigned t = (g << 2) | (r & 3);
    float4 s = *reinterpret_cast<const float4*>(src + 4 * t);
    float z1 = b1[j];
    z1 = __builtin_fmaf(Wih1[j * 3 + 0], s.x, z1);
    z1 = __builtin_fmaf(Wih1[j * 3 + 1], s.z, z1);
    z1 = __builtin_fmaf(Wih1[j * 3 + 2], s.w, z1);
    float z2 = b2[j];
    z2 = __builtin_fmaf(Wih2[j * 3 + 0], s.y, z2);
    z2 = __builtin_fmaf(Wih2[j * 3 + 1], s.z, z2);
    z2 = __builtin_fmaf(Wih2[j * 3 + 2], s.w, z2);
    zxG1[n] = z1;
    zxG2[n] = z2;
}

// ---------------------------------------------------------------------------
// K2: fold linear layers into LSTM3's input projection.
// ---------------------------------------------------------------------------
__global__ void fold_kernel(const float* __restrict__ Wih3,
                            const float* __restrict__ W1, const float* __restrict__ bl1,
                            const float* __restrict__ W2, const float* __restrict__ bl2,
                            const float* __restrict__ b3,
                            float* __restrict__ M1, float* __restrict__ M2,
                            float* __restrict__ b3p)
{
    int idx = blockIdx.x * blockDim.x + threadIdx.x;
    if (idx < GDIM * HDIM) {
        int j = idx / HDIM, k = idx - j * HDIM;
        M1[idx] = Wih3[j * 50 + 0] * W1[k];
        float s = 0.0f;
        for (int m = 0; m < 49; ++m)
            s = __builtin_fmaf(Wih3[j * 50 + 1 + m], W2[m * HDIM + k], s);
        M2[idx] = s;
    }
    if (idx < GDIM) {
        float s = b3[idx] + Wih3[idx * 50 + 0] * bl1[0];
        for (int m = 0; m < 49; ++m)
            s = __builtin_fmaf(Wih3[idx * 50 + 1 + m], bl2[m], s);
        b3p[idx] = s;
    }
}

// ---------------------------------------------------------------------------
// K3: CHUNKED fused 3-LSTM scan. One block, 3 waves:
//   wave0 = LSTM1, wave1 = LSTM2: compute CHUNK=16 steps, write folded
//           projections (M*h) into LDS part[wid][buf][s][row].
//   wave2 = LSTM3: one chunk behind, assembles zx3 from LDS partials.
// ONE __syncthreads per 16 steps. zx loads prefetched a full chunk ahead.
// This round: all fp32 divisions replaced by v_rcp_f32 (-25-30 instr/step).
// ---------------------------------------------------------------------------
#define RL(h_, l_) __int_as_float(__builtin_amdgcn_readlane(__float_as_int(h_), 32 + (l_)))

#define BCAST_H(h_)                                                        \
    hs_0  = RL(h_, 0);  hs_1  = RL(h_, 1);  hs_2  = RL(h_, 2);             \
    hs_3  = RL(h_, 3);  hs_4  = RL(h_, 4);  hs_5  = RL(h_, 5);             \
    hs_6  = RL(h_, 6);  hs_7  = RL(h_, 7);  hs_8  = RL(h_, 8);             \
    hs_9  = RL(h_, 9);  hs_10 = RL(h_, 10); hs_11 = RL(h_, 11);            \
    hs_12 = RL(h_, 12); hs_13 = RL(h_, 13); hs_14 = RL(h_, 14);            \
    hs_15 = RL(h_, 15); hs_16 = RL(h_, 16); hs_17 = RL(h_, 17);            \
    hs_18 = RL(h_, 18); hs_19 = RL(h_, 19); hs_20 = RL(h_, 20);

// gates from zA_,zB_; updates c; defines hW; broadcasts to hs_*
#define STEP_CORE(zA_, zB_)                                                \
        float a0 = (zA_), a1 = 0.0f, a2 = 0.0f;                            \
        float b0 = (zB_), b1 = 0.0f, b2 = 0.0f;                            \
        a0 = __builtin_fmaf(wa_0,  hs_0,  a0);                             \
        b0 = __builtin_fmaf(wb_0,  hs_0,  b0);                             \
        a0 = __builtin_fmaf(wa_1,  hs_1,  a0);                             \
        b0 = __builtin_fmaf(wb_1,  hs_1,  b0);                             \
        a0 = __builtin_fmaf(wa_2,  hs_2,  a0);                             \
        b0 = __builtin_fmaf(wb_2,  hs_2,  b0);                             \
        a0 = __builtin_fmaf(wa_3,  hs_3,  a0);                             \
        b0 = __builtin_fmaf(wb_3,  hs_3,  b0);                             \
        a0 = __builtin_fmaf(wa_4,  hs_4,  a0);                             \
        b0 = __builtin_fmaf(wb_4,  hs_4,  b0);                             \
        a0 = __builtin_fmaf(wa_5,  hs_5,  a0);                             \
        b0 = __builtin_fmaf(wb_5,  hs_5,  b0);                             \
        a0 = __builtin_fmaf(wa_6,  hs_6,  a0);                             \
        b0 = __builtin_fmaf(wb_6,  hs_6,  b0);                             \
        a1 = __builtin_fmaf(wa_7,  hs_7,  a1);                             \
        b1 = __builtin_fmaf(wb_7,  hs_7,  b1);                             \
        a1 = __builtin_fmaf(wa_8,  hs_8,  a1);                             \
        b1 = __builtin_fmaf(wb_8,  hs_8,  b1);                             \
        a1 = __builtin_fmaf(wa_9,  hs_9,  a1);                             \
        b1 = __builtin_fmaf(wb_9,  hs_9,  b1);                             \
        a1 = __builtin_fmaf(wa_10, hs_10, a1);                             \
        b1 = __builtin_fmaf(wb_10, hs_10, b1);                             \
        a1 = __builtin_fmaf(wa_11, hs_11, a1);                             \
        b1 = __builtin_fmaf(wb_11, hs_11, b1);                             \
        a1 = __builtin_fmaf(wa_12, hs_12, a1);                             \
        b1 = __builtin_fmaf(wb_12, hs_12, b1);                             \
        a1 = __builtin_fmaf(wa_13, hs_13, a1);                             \
        b1 = __builtin_fmaf(wb_13, hs_13, b1);                             \
        a2 = __builtin_fmaf(wa_14, hs_14, a2);                             \
        b2 = __builtin_fmaf(wb_14, hs_14, b2);                             \
        a2 = __builtin_fmaf(wa_15, hs_15, a2);                             \
        b2 = __builtin_fmaf(wb_15, hs_15, b2);                             \
        a2 = __builtin_fmaf(wa_16, hs_16, a2);                             \
        b2 = __builtin_fmaf(wb_16, hs_16, b2);                             \
        a2 = __builtin_fmaf(wa_17, hs_17, a2);                             \
        b2 = __builtin_fmaf(wb_17, hs_17, b2);                             \
        a2 = __builtin_fmaf(wa_18, hs_18, a2);                             \
        b2 = __builtin_fmaf(wb_18, hs_18, b2);                             \
        a2 = __builtin_fmaf(wa_19, hs_19, a2);                             \
        b2 = __builtin_fmaf(wb_19, hs_19, b2);                             \
        a2 = __builtin_fmaf(wa_20, hs_20, a2);                             \
        b2 = __builtin_fmaf(wb_20, hs_20, b2);                             \
        float accA = (a0 + a1) + a2;                                       \
        float accB = (b0 + b1) + b2;                                       \
        float vA = sigm(accA);                                             \
        float vB = __builtin_fmaf(mBc, sigm(sB * accB), aB);               \
        float p_  = vA * vB;                                               \
        float pSw = __shfl_xor(p_, 32);                                    \
        c = __builtin_fmaf(vA, c, pSw);                                    \
        float th_ = tanh_stable(c);                                        \
        float hW  = vB * th_;                                              \
        BCAST_H(hW)

// waves 0/1: one step + folded projection into LDS at slot s_
#define W01_STEP(s_, zA_, zB_)                                             \
    {                                                                      \
        STEP_CORE(zA_, zB_)                                                \
        float pa0 = 0, pa1 = 0, pa2 = 0, pb0 = 0, pb1 = 0, pb2 = 0;        \
        pa0 = __builtin_fmaf(ma_0,  hs_0,  pa0);                           \
        pb0 = __builtin_fmaf(mb_0,  hs_0,  pb0);                           \
        pa0 = __builtin_fmaf(ma_1,  hs_1,  pa0);                           \
        pb0 = __builtin_fmaf(mb_1,  hs_1,  pb0);                           \
        pa0 = __builtin_fmaf(ma_2,  hs_2,  pa0);                           \
        pb0 = __builtin_fmaf(mb_2,  hs_2,  pb0);                           \
        pa0 = __builtin_fmaf(ma_3,  hs_3,  pa0);                           \
        pb0 = __builtin_fmaf(mb_3,  hs_3,  pb0);                           \
        pa0 = __builtin_fmaf(ma_4,  hs_4,  pa0);                           \
        pb0 = __builtin_fmaf(mb_4,  hs_4,  pb0);                           \
        pa0 = __builtin_fmaf(ma_5,  hs_5,  pa0);                           \
        pb0 = __builtin_fmaf(mb_5,  hs_5,  pb0);                           \
        pa0 = __builtin_fmaf(ma_6,  hs_6,  pa0);                           \
        pb0 = __builtin_fmaf(mb_6,  hs_6,  pb0);                           \
        pa1 = __builtin_fmaf(ma_7,  hs_7,  pa1);                           \
        pb1 = __builtin_fmaf(mb_7,  hs_7,  pb1);                           \
        pa1 = __builtin_fmaf(ma_8,  hs_8,  pa1);                           \
        pb1 = __builtin_fmaf(mb_8,  hs_8,  pb1);                           \
        pa1 = __builtin_fmaf(ma_9,  hs_9,  pa1);                           \
        pb1 = __builtin_fmaf(mb_9,  hs_9,  pb1);                           \
        pa1 = __builtin_fmaf(ma_10, hs_10, pa1);                           \
        pb1 = __builtin_fmaf(mb_10, hs_10, pb1);                           \
        pa1 = __builtin_fmaf(ma_11, hs_11, pa1);                           \
        pb1 = __builtin_fmaf(mb_11, hs_11, pb1);                           \
        pa1 = __builtin_fmaf(ma_12, hs_12, pa1);                           \
        pb1 = __builtin_fmaf(mb_12, hs_12, pb1);                           \
        pa1 = __builtin_fmaf(ma_13, hs_13, pa1);                           \
        pb1 = __builtin_fmaf(mb_13, hs_13, pb1);                           \
        pa2 = __builtin_fmaf(ma_14, hs_14, pa2);                           \
        pb2 = __builtin_fmaf(mb_14, hs_14, pb2);                           \
        pa2 = __builtin_fmaf(ma_15, hs_15, pa2);                           \
        pb2 = __builtin_fmaf(mb_15, hs_15, pb2);                           \
        pa2 = __builtin_fmaf(ma_16, hs_16, pa2);                           \
        pb2 = __builtin_fmaf(mb_16, hs_16, pb2);                           \
        pa2 = __builtin_fmaf(ma_17, hs_17, pa2);                           \
        pb2 = __builtin_fmaf(mb_17, hs_17, pb2);                           \
        pa2 = __builtin_fmaf(ma_18, hs_18, pa2);                           \
        pb2 = __builtin_fmaf(mb_18, hs_18, pb2);                           \
        pa2 = __builtin_fmaf(ma_19, hs_19, pa2);                           \
        pb2 = __builtin_fmaf(mb_19, hs_19, pb2);                           \
        pa2 = __builtin_fmaf(ma_20, hs_20, pa2);                           \
        pb2 = __builtin_fmaf(mb_20, hs_20, pb2);                           \
        if (act) {                                                         \
            pp[(s_) * GDIM + rowA] = (pa0 + pa1) + pa2;                    \
            pp[(s_) * GDIM + rowB] = (pb0 + pb1) + pb2;                    \
        }                                                                  \
    }

// wave2: one LSTM3 step from LDS partials at slot s_
#define W2_STEP(s_)                                                        \
    {                                                                      \
        float zA = b3A + p0[(s_) * GDIM + rowA] + p1[(s_) * GDIM + rowA];  \
        float zB = b3B + p0[(s_) * GDIM + rowB] + p1[(s_) * GDIM + rowB];  \
        STEP_CORE(zA, zB)                                                  \
        if (hi && act) h3out[(tbase + (s_)) * HDIM + k] = hW;              \
    }

#define LDG4(p_) (*reinterpret_cast<const float4*>(p_))

__global__ __launch_bounds__(192, 1)
void fused_scan_kernel(const float* __restrict__ zxG1, const float* __restrict__ Whh1,
                       const float* __restrict__ M1,
                       const float* __restrict__ zxG2, const float* __restrict__ Whh2,
                       const float* __restrict__ M2,
                       const float* __restrict__ Whh3, const float* __restrict__ b3p,
                       float* __restrict__ h3out)
{
    __shared__ float part[2][2][CHUNK][GDIM];   // [lstm][buf][step][row] = 21.5KB

    const int wid  = threadIdx.x >> 6;   // 0,1,2
    const int lane = threadIdx.x & 63;
    const int k = lane & 31;
    const bool hi = lane >= 32;
    const bool act = k < HDIM;
    const int kk = act ? k : 0;

    const int rowA = hi ? (HDIM + kk)     : kk;              // f : i  (sigmoid)
    const int rowB = hi ? (3 * HDIM + kk) : (2 * HDIM + kk); // o : g
    const float sB  = hi ? 1.0f : 2.0f;  // lo: tanh via 2*sigm(2x)-1 ; hi: sigm
    const float mBc = hi ? 1.0f : 2.0f;
    const float aB  = hi ? 0.0f : -1.0f;

    const float* Whh = (wid == 0) ? Whh1 : (wid == 1) ? Whh2 : Whh3;
    const float* zxG = (wid == 1) ? zxG2 : zxG1;                 // dummy for wid2
    const float* Mm  = (wid == 0) ? M1 : (wid == 1) ? M2 : Whh3; // dummy for wid2

    const float* WA = Whh + rowA * HDIM;
    const float* WB = Whh + rowB * HDIM;
    const float* MA = Mm  + rowA * HDIM;
    const float* MB = Mm  + rowB * HDIM;

    // recurrent weights: 42 named scalars
    float wa_0  = WA[0],  wa_1  = WA[1],  wa_2  = WA[2],  wa_3  = WA[3];
    float wa_4  = WA[4],  wa_5  = WA[5],  wa_6  = WA[6],  wa_7  = WA[7];
    float wa_8  = WA[8],  wa_9  = WA[9],  wa_10 = WA[10], wa_11 = WA[11];
    float wa_12 = WA[12], wa_13 = WA[13], wa_14 = WA[14], wa_15 = WA[15];
    float wa_16 = WA[16], wa_17 = WA[17], wa_18 = WA[18], wa_19 = WA[19];
    float wa_20 = WA[20];
    float wb_0  = WB[0],  wb_1  = WB[1],  wb_2  = WB[2],  wb_3  = WB[3];
    float wb_4  = WB[4],  wb_5  = WB[5],  wb_6  = WB[6],  wb_7  = WB[7];
    float wb_8  = WB[8],  wb_9  = WB[9],  wb_10 = WB[10], wb_11 = WB[11];
    float wb_12 = WB[12], wb_13 = WB[13], wb_14 = WB[14], wb_15 = WB[15];
    float wb_16 = WB[16], wb_17 = WB[17], wb_18 = WB[18], wb_19 = WB[19];
    float wb_20 = WB[20];

    // projection weights (waves 0/1; harmless garbage for wave2)
    float ma_0  = MA[0],  ma_1  = MA[1],  ma_2  = MA[2],  ma_3  = MA[3];
    float ma_4  = MA[4],  ma_5  = MA[5],  ma_6  = MA[6],  ma_7  = MA[7];
    float ma_8  = MA[8],  ma_9  = MA[9],  ma_10 = MA[10], ma_11 = MA[11];
    float ma_12 = MA[12], ma_13 = MA[13], ma_14 = MA[14], ma_15 = MA[15];
    float ma_16 = MA[16], ma_17 = MA[17], ma_18 = MA[18], ma_19 = MA[19];
    float ma_20 = MA[20];
    float mb_0  = MB[0],  mb_1  = MB[1],  mb_2  = MB[2],  mb_3  = MB[3];
    float mb_4  = MB[4],  mb_5  = MB[5],  mb_6  = MB[6],  mb_7  = MB[7];
    float mb_8  = MB[8],  mb_9  = MB[9],  mb_10 = MB[10], mb_11 = MB[11];
    float mb_12 = MB[12], mb_13 = MB[13], mb_14 = MB[14], mb_15 = MB[15];
    float mb_16 = MB[16], mb_17 = MB[17], mb_18 = MB[18], mb_19 = MB[19];
    float mb_20 = MB[20];

    const float b3A = b3p[rowA];
    const float b3B = b3p[rowB];

    // state
    float hs_0 = 0, hs_1 = 0, hs_2 = 0, hs_3 = 0, hs_4 = 0, hs_5 = 0, hs_6 = 0;
    float hs_7 = 0, hs_8 = 0, hs_9 = 0, hs_10 = 0, hs_11 = 0, hs_12 = 0;
    float hs_13 = 0, hs_14 = 0, hs_15 = 0, hs_16 = 0, hs_17 = 0, hs_18 = 0;
    float hs_19 = 0, hs_20 = 0;
    float c = 0.0f;

    // zx chunk registers (waves 0/1): current chunk = 4 groups x 2 rows
    const float* baseA = zxG + rowA * 4;
    const float* baseB = zxG + rowB * 4;
    float4 cA0, cA1, cA2, cA3, cB0, cB1, cB2, cB3;
    if (wid < 2) {
        cA0 = LDG4(baseA + 0 * GSTRIDE); cA1 = LDG4(baseA + 1 * GSTRIDE);
        cA2 = LDG4(baseA + 2 * GSTRIDE); cA3 = LDG4(baseA + 3 * GSTRIDE);
        cB0 = LDG4(baseB + 0 * GSTRIDE); cB1 = LDG4(baseB + 1 * GSTRIDE);
        cB2 = LDG4(baseB + 2 * GSTRIDE); cB3 = LDG4(baseB + 3 * GSTRIDE);
    }

#pragma unroll 1
    for (int i = 0; i <= NCHUNK; ++i) {
        // prefetch next chunk (clamped in-bounds; waits land a full chunk later)
        float4 nA0, nA1, nA2, nA3, nB0, nB1, nB2, nB3;
        if (wid < 2) {
            const int gn = (i + 1 < NCHUNK) ? (i + 1) : (NCHUNK - 1);
            const float* pA = baseA + (size_t)gn * 4 * GSTRIDE;
            const float* pB = baseB + (size_t)gn * 4 * GSTRIDE;
            nA0 = LDG4(pA + 0 * GSTRIDE); nA1 = LDG4(pA + 1 * GSTRIDE);
            nA2 = LDG4(pA + 2 * GSTRIDE); nA3 = LDG4(pA + 3 * GSTRIDE);
            nB0 = LDG4(pB + 0 * GSTRIDE); nB1 = LDG4(pB + 1 * GSTRIDE);
            nB2 = LDG4(pB + 2 * GSTRIDE); nB3 = LDG4(pB + 3 * GSTRIDE);

            if (i < NCHUNK) {
                float* pp = &part[wid][i & 1][0][0];
                W01_STEP(0,  cA0.x, cB0.x) W01_STEP(1,  cA0.y, cB0.y)
                W01_STEP(2,  cA0.z, cB0.z) W01_STEP(3,  cA0.w, cB0.w)
                W01_STEP(4,  cA1.x, cB1.x) W01_STEP(5,  cA1.y, cB1.y)
                W01_STEP(6,  cA1.z, cB1.z) W01_STEP(7,  cA1.w, cB1.w)
                W01_STEP(8,  cA2.x, cB2.x) W01_STEP(9,  cA2.y, cB2.y)
                W01_STEP(10, cA2.z, cB2.z) W01_STEP(11, cA2.w, cB2.w)
                W01_STEP(12, cA3.x, cB3.x) W01_STEP(13, cA3.y, cB3.y)
                W01_STEP(14, cA3.z, cB3.z) W01_STEP(15, cA3.w, cB3.w)
            }
        } else if (i >= 1) {
            const int buf = (i - 1) & 1;
            const int tbase = (i - 1) * CHUNK;
            const float* p0 = &part[0][buf][0][0];
            const float* p1 = &part[1][buf][0][0];
            W2_STEP(0)  W2_STEP(1)  W2_STEP(2)  W2_STEP(3)
            W2_STEP(4)  W2_STEP(5)  W2_STEP(6)  W2_STEP(7)
            W2_STEP(8)  W2_STEP(9)  W2_STEP(10) W2_STEP(11)
            W2_STEP(12) W2_STEP(13) W2_STEP(14) W2_STEP(15)
        }
        __syncthreads();
        if (wid < 2) {
            cA0 = nA0; cA1 = nA1; cA2 = nA2; cA3 = nA3;
            cB0 = nB0; cB1 = nB1; cB2 = nB2; cB3 = nB3;
        }
    }
}

// ---------------------------------------------------------------------------
// K4: final linear: out[t] = h3[t] @ W3.T + bl3   (W3: [2,21])
// ---------------------------------------------------------------------------
__global__ void out_kernel(const float* __restrict__ h3, const float* __restrict__ W3,
                           const float* __restrict__ bl3, float* __restrict__ out)
{
    int t = blockIdx.x * blockDim.x + threadIdx.x;
    if (t >= T_LEN) return;
    float s0 = bl3[0], s1 = bl3[1];
#pragma unroll
    for (int kq = 0; kq < HDIM; ++kq) {
        float h = h3[t * HDIM + kq];
        s0 = __builtin_fmaf(W3[kq], h, s0);
        s1 = __builtin_fmaf(W3[HDIM + kq], h, s1);
    }
    out[t * 2 + 0] = s0;
    out[t * 2 + 1] = s1;
}

extern "C" void kernel_launch(void* const* d_in, const int* in_sizes, int n_in,
                              void* d_out, int out_size, void* d_ws, size_t ws_size,
                              hipStream_t stream) {
    const float* src  = (const float*)d_in[0];
    const float* Wih1 = (const float*)d_in[1];
    const float* Whh1 = (const float*)d_in[2];
    const float* b1   = (const float*)d_in[3];
    const float* W1   = (const float*)d_in[4];
    const float* bl1  = (const float*)d_in[5];
    const float* Wih2 = (const float*)d_in[6];
    const float* Whh2 = (const float*)d_in[7];
    const float* b2   = (const float*)d_in[8];
    const float* W2   = (const float*)d_in[9];
    const float* bl2  = (const float*)d_in[10];
    const float* Wih3 = (const float*)d_in[11];
    const float* Whh3 = (const float*)d_in[12];
    const float* b3   = (const float*)d_in[13];
    const float* W3   = (const float*)d_in[14];
    const float* bl3  = (const float*)d_in[15];
    float* out = (float*)d_out;

    float* ws   = (float*)d_ws;
    float* zxG1 = ws;
    float* zxG2 = zxG1 + (size_t)T_LEN * GDIM;
    float* h3   = zxG2 + (size_t)T_LEN * GDIM;
    float* M1   = h3   + (size_t)T_LEN * HDIM;
    float* M2   = M1   + GDIM * HDIM;
    float* b3p  = M2   + GDIM * HDIM;

    zx12_kernel<<<(T_LEN * GDIM + 255) / 256, 256, 0, stream>>>(
        src, Wih1, b1, Wih2, b2, zxG1, zxG2);
    fold_kernel<<<(GDIM * HDIM + 255) / 256, 256, 0, stream>>>(
        Wih3, W1, bl1, W2, bl2, b3, M1, M2, b3p);
    fused_scan_kernel<<<1, 192, 0, stream>>>(
        zxG1, Whh1, M1, zxG2, Whh2, M2, Whh3, b3p, h3);
    out_kernel<<<(T_LEN + 255) / 256, 256, 0, stream>>>(h3, W3, bl3, out);
}

// Round 13
// 2286.502 us; speedup vs baseline: 1.9312x; 1.2677x over previous
//
#include <hip/hip_runtime.h>
#include <hip/hip_bf16.h>

// Problem constants (from reference): T=8192 steps, batch=1, H=21 hidden.
#define T_LEN 8192
#define HDIM  21
#define GDIM  84           // 4*H gate rows
#define NGRP  (T_LEN / 4)  // 2048 groups of 4 timesteps
#define GSTRIDE (GDIM * 4) // 336 floats per group block
#define CHUNK 16           // steps per fused superstep (4 groups)
#define NCHUNK (T_LEN / CHUNK) // 512

typedef float floatx2 __attribute__((ext_vector_type(2)));

// packed FMA: acc.{x,y} += w.{x,y} * hs(low 32 bits of SGPR pair, both halves)
#define PKFMA(acc_, w_, h_)                                                \
    asm("v_pk_fma_f32 %0, %1, %2, %0 op_sel_hi:[1,0,1]"                    \
        : "+v"(acc_) : "v"(w_), "s"(h_))

__device__ __forceinline__ float rcp_fast(float x) {
    return __builtin_amdgcn_rcpf(x);     // v_rcp_f32, ~1ulp
}
__device__ __forceinline__ float sigm(float x) {
    return rcp_fast(1.0f + __expf(-x));  // stable both directions
}
__device__ __forceinline__ float tanh_stable(float x) {
    float e = __expf(2.0f * x);          // +inf -> 1, -inf -> -1, no inf/inf
    return __builtin_fmaf(-2.0f, rcp_fast(e + 1.0f), 1.0f);
}

// ---------------------------------------------------------------------------
// K1: parallel input projections, GROUPED output zxG[g][j][q] (coalesced).
// ---------------------------------------------------------------------------
__global__ void zx12_kernel(const float* __restrict__ src,
                            const float* __restrict__ Wih1, const float* __restrict__ b1,
                            const float* __restrict__ Wih2, const float* __restrict__ b2,
                            float* __restrict__ zxG1, float* __restrict__ zxG2)
{
    int n = blockIdx.x * blockDim.x + threadIdx.x;
    if (n >= T_LEN * GDIM) return;
    unsigned g = (unsigned)n / GSTRIDE;
    unsigned r = (unsigned)n - g * GSTRIDE;
    unsigned j = r >> 2;
    unsigned t = (g << 2) | (r & 3);
    float4 s = *reinterpret_cast<const float4*>(src + 4 * t);
    float z1 = b1[j];
    z1 = __builtin_fmaf(Wih1[j * 3 + 0], s.x, z1);
    z1 = __builtin_fmaf(Wih1[j * 3 + 1], s.z, z1);
    z1 = __builtin_fmaf(Wih1[j * 3 + 2], s.w, z1);
    float z2 = b2[j];
    z2 = __builtin_fmaf(Wih2[j * 3 + 0], s.y, z2);
    z2 = __builtin_fmaf(Wih2[j * 3 + 1], s.z, z2);
    z2 = __builtin_fmaf(Wih2[j * 3 + 2], s.w, z2);
    zxG1[n] = z1;
    zxG2[n] = z2;
}

// ---------------------------------------------------------------------------
// K2: fold linear layers into LSTM3's input projection.
// ---------------------------------------------------------------------------
__global__ void fold_kernel(const float* __restrict__ Wih3,
                            const float* __restrict__ W1, const float* __restrict__ bl1,
                            const float* __restrict__ W2, const float* __restrict__ bl2,
                            const float* __restrict__ b3,
                            float* __restrict__ M1, float* __restrict__ M2,
                            float* __restrict__ b3p)
{
    int idx = blockIdx.x * blockDim.x + threadIdx.x;
    if (idx < GDIM * HDIM) {
        int j = idx / HDIM, k = idx - j * HDIM;
        M1[idx] = Wih3[j * 50 + 0] * W1[k];
        float s = 0.0f;
        for (int m = 0; m < 49; ++m)
            s = __builtin_fmaf(Wih3[j * 50 + 1 + m], W2[m * HDIM + k], s);
        M2[idx] = s;
    }
    if (idx < GDIM) {
        float s = b3[idx] + Wih3[idx * 50 + 0] * bl1[0];
        for (int m = 0; m < 49; ++m)
            s = __builtin_fmaf(Wih3[idx * 50 + 1 + m], bl2[m], s);
        b3p[idx] = s;
    }
}

// ---------------------------------------------------------------------------
// K3: CHUNKED fused 3-LSTM scan, PACKED-FMA edition.
//   wave0 = LSTM1, wave1 = LSTM2 (+ M*h projection into LDS, pk-paired)
//   wave2 = LSTM3, one chunk behind.
// (accA,accB) and (pa,pb) run as float2 chains on v_pk_fma_f32; the shared
// hs_j scalar is an SGPR pair read with op_sel_hi:[1,0,1] (low-word bcast).
// ---------------------------------------------------------------------------
#define RLI(h_, l_) __builtin_amdgcn_readlane(__float_as_int(h_), 32 + (l_))

#define BCAST_H(h_)                                                        \
    hsL_0  = (unsigned)RLI(h_, 0);  hsL_1  = (unsigned)RLI(h_, 1);         \
    hsL_2  = (unsigned)RLI(h_, 2);  hsL_3  = (unsigned)RLI(h_, 3);         \
    hsL_4  = (unsigned)RLI(h_, 4);  hsL_5  = (unsigned)RLI(h_, 5);         \
    hsL_6  = (unsigned)RLI(h_, 6);  hsL_7  = (unsigned)RLI(h_, 7);         \
    hsL_8  = (unsigned)RLI(h_, 8);  hsL_9  = (unsigned)RLI(h_, 9);         \
    hsL_10 = (unsigned)RLI(h_, 10); hsL_11 = (unsigned)RLI(h_, 11);        \
    hsL_12 = (unsigned)RLI(h_, 12); hsL_13 = (unsigned)RLI(h_, 13);        \
    hsL_14 = (unsigned)RLI(h_, 14); hsL_15 = (unsigned)RLI(h_, 15);        \
    hsL_16 = (unsigned)RLI(h_, 16); hsL_17 = (unsigned)RLI(h_, 17);        \
    hsL_18 = (unsigned)RLI(h_, 18); hsL_19 = (unsigned)RLI(h_, 19);        \
    hsL_20 = (unsigned)RLI(h_, 20);

// gates from zA_,zB_; updates c; defines hW; broadcasts to hsL_*
#define STEP_CORE(zA_, zB_)                                                \
        floatx2 q0, q1, q2;                                                \
        q0.x = (zA_); q0.y = (zB_);                                        \
        q1 = (floatx2)0.0f; q2 = (floatx2)0.0f;                            \
        PKFMA(q0, wab_0,  hsL_0);                                          \
        PKFMA(q1, wab_7,  hsL_7);                                          \
        PKFMA(q2, wab_14, hsL_14);                                         \
        PKFMA(q0, wab_1,  hsL_1);                                          \
        PKFMA(q1, wab_8,  hsL_8);                                          \
        PKFMA(q2, wab_15, hsL_15);                                         \
        PKFMA(q0, wab_2,  hsL_2);                                          \
        PKFMA(q1, wab_9,  hsL_9);                                          \
        PKFMA(q2, wab_16, hsL_16);                                         \
        PKFMA(q0, wab_3,  hsL_3);                                          \
        PKFMA(q1, wab_10, hsL_10);                                         \
        PKFMA(q2, wab_17, hsL_17);                                         \
        PKFMA(q0, wab_4,  hsL_4);                                          \
        PKFMA(q1, wab_11, hsL_11);                                         \
        PKFMA(q2, wab_18, hsL_18);                                         \
        PKFMA(q0, wab_5,  hsL_5);                                          \
        PKFMA(q1, wab_12, hsL_12);                                         \
        PKFMA(q2, wab_19, hsL_19);                                         \
        PKFMA(q0, wab_6,  hsL_6);                                          \
        PKFMA(q1, wab_13, hsL_13);                                         \
        PKFMA(q2, wab_20, hsL_20);                                         \
        floatx2 qt = (q0 + q1) + q2;                                       \
        float accA = qt.x;                                                 \
        float accB = qt.y;                                                 \
        float vA = sigm(accA);                                             \
        float vB = __builtin_fmaf(mBc, sigm(sB * accB), aB);               \
        float p_  = vA * vB;                                               \
        float pSw = __shfl_xor(p_, 32);                                    \
        c = __builtin_fmaf(vA, c, pSw);                                    \
        float th_ = tanh_stable(c);                                        \
        float hW  = vB * th_;                                              \
        BCAST_H(hW)

// waves 0/1: one step + packed folded projection into LDS at slot s_
#define W01_STEP(s_, zA_, zB_)                                             \
    {                                                                      \
        STEP_CORE(zA_, zB_)                                                \
        floatx2 r0, r1, r2;                                                \
        r0 = (floatx2)0.0f; r1 = (floatx2)0.0f; r2 = (floatx2)0.0f;        \
        PKFMA(r0, mab_0,  hsL_0);                                          \
        PKFMA(r1, mab_7,  hsL_7);                                          \
        PKFMA(r2, mab_14, hsL_14);                                         \
        PKFMA(r0, mab_1,  hsL_1);                                          \
        PKFMA(r1, mab_8,  hsL_8);                                          \
        PKFMA(r2, mab_15, hsL_15);                                         \
        PKFMA(r0, mab_2,  hsL_2);                                          \
        PKFMA(r1, mab_9,  hsL_9);                                          \
        PKFMA(r2, mab_16, hsL_16);                                         \
        PKFMA(r0, mab_3,  hsL_3);                                          \
        PKFMA(r1, mab_10, hsL_10);                                         \
        PKFMA(r2, mab_17, hsL_17);                                         \
        PKFMA(r0, mab_4,  hsL_4);                                          \
        PKFMA(r1, mab_11, hsL_11);                                         \
        PKFMA(r2, mab_18, hsL_18);                                         \
        PKFMA(r0, mab_5,  hsL_5);                                          \
        PKFMA(r1, mab_12, hsL_12);                                         \
        PKFMA(r2, mab_19, hsL_19);                                         \
        PKFMA(r0, mab_6,  hsL_6);                                          \
        PKFMA(r1, mab_13, hsL_13);                                         \
        PKFMA(r2, mab_20, hsL_20);                                         \
        floatx2 rt = (r0 + r1) + r2;                                       \
        if (act) {                                                         \
            pp[(s_) * GDIM + rowA] = rt.x;                                 \
            pp[(s_) * GDIM + rowB] = rt.y;                                 \
        }                                                                  \
    }

// wave2: one LSTM3 step from LDS partials at slot s_
#define W2_STEP(s_)                                                        \
    {                                                                      \
        float zA = b3A + p0[(s_) * GDIM + rowA] + p1[(s_) * GDIM + rowA];  \
        float zB = b3B + p0[(s_) * GDIM + rowB] + p1[(s_) * GDIM + rowB];  \
        STEP_CORE(zA, zB)                                                  \
        if (hi && act) h3out[(tbase + (s_)) * HDIM + k] = hW;              \
    }

#define LDG4(p_) (*reinterpret_cast<const float4*>(p_))

__global__ __launch_bounds__(192, 1)
void fused_scan_kernel(const float* __restrict__ zxG1, const float* __restrict__ Whh1,
                       const float* __restrict__ M1,
                       const float* __restrict__ zxG2, const float* __restrict__ Whh2,
                       const float* __restrict__ M2,
                       const float* __restrict__ Whh3, const float* __restrict__ b3p,
                       float* __restrict__ h3out)
{
    __shared__ float part[2][2][CHUNK][GDIM];   // [lstm][buf][step][row] = 21.5KB

    const int wid  = threadIdx.x >> 6;   // 0,1,2
    const int lane = threadIdx.x & 63;
    const int k = lane & 31;
    const bool hi = lane >= 32;
    const bool act = k < HDIM;
    const int kk = act ? k : 0;

    const int rowA = hi ? (HDIM + kk)     : kk;              // f : i  (sigmoid)
    const int rowB = hi ? (3 * HDIM + kk) : (2 * HDIM + kk); // o : g
    const float sB  = hi ? 1.0f : 2.0f;  // lo: tanh via 2*sigm(2x)-1 ; hi: sigm
    const float mBc = hi ? 1.0f : 2.0f;
    const float aB  = hi ? 0.0f : -1.0f;

    const float* Whh = (wid == 0) ? Whh1 : (wid == 1) ? Whh2 : Whh3;
    const float* zxG = (wid == 1) ? zxG2 : zxG1;                 // dummy for wid2
    const float* Mm  = (wid == 0) ? M1 : (wid == 1) ? M2 : Whh3; // dummy for wid2

    const float* WA = Whh + rowA * HDIM;
    const float* WB = Whh + rowB * HDIM;
    const float* MA = Mm  + rowA * HDIM;
    const float* MB = Mm  + rowB * HDIM;

    // recurrent weights packed (wa_j, wb_j): 21 VGPR pairs
    floatx2 wab_0,  wab_1,  wab_2,  wab_3,  wab_4,  wab_5,  wab_6;
    floatx2 wab_7,  wab_8,  wab_9,  wab_10, wab_11, wab_12, wab_13;
    floatx2 wab_14, wab_15, wab_16, wab_17, wab_18, wab_19, wab_20;
    wab_0.x  = WA[0];  wab_0.y  = WB[0];   wab_1.x  = WA[1];  wab_1.y  = WB[1];
    wab_2.x  = WA[2];  wab_2.y  = WB[2];   wab_3.x  = WA[3];  wab_3.y  = WB[3];
    wab_4.x  = WA[4];  wab_4.y  = WB[4];   wab_5.x  = WA[5];  wab_5.y  = WB[5];
    wab_6.x  = WA[6];  wab_6.y  = WB[6];   wab_7.x  = WA[7];  wab_7.y  = WB[7];
    wab_8.x  = WA[8];  wab_8.y  = WB[8];   wab_9.x  = WA[9];  wab_9.y  = WB[9];
    wab_10.x = WA[10]; wab_10.y = WB[10];  wab_11.x = WA[11]; wab_11.y = WB[11];
    wab_12.x = WA[12]; wab_12.y = WB[12];  wab_13.x = WA[13]; wab_13.y = WB[13];
    wab_14.x = WA[14]; wab_14.y = WB[14];  wab_15.x = WA[15]; wab_15.y = WB[15];
    wab_16.x = WA[16]; wab_16.y = WB[16];  wab_17.x = WA[17]; wab_17.y = WB[17];
    wab_18.x = WA[18]; wab_18.y = WB[18];  wab_19.x = WA[19]; wab_19.y = WB[19];
    wab_20.x = WA[20]; wab_20.y = WB[20];

    // projection weights packed (ma_j, mb_j)
    floatx2 mab_0,  mab_1,  mab_2,  mab_3,  mab_4,  mab_5,  mab_6;
    floatx2 mab_7,  mab_8,  mab_9,  mab_10, mab_11, mab_12, mab_13;
    floatx2 mab_14, mab_15, mab_16, mab_17, mab_18, mab_19, mab_20;
    mab_0.x  = MA[0];  mab_0.y  = MB[0];   mab_1.x  = MA[1];  mab_1.y  = MB[1];
    mab_2.x  = MA[2];  mab_2.y  = MB[2];   mab_3.x  = MA[3];  mab_3.y  = MB[3];
    mab_4.x  = MA[4];  mab_4.y  = MB[4];   mab_5.x  = MA[5];  mab_5.y  = MB[5];
    mab_6.x  = MA[6];  mab_6.y  = MB[6];   mab_7.x  = MA[7];  mab_7.y  = MB[7];
    mab_8.x  = MA[8];  mab_8.y  = MB[8];   mab_9.x  = MA[9];  mab_9.y  = MB[9];
    mab_10.x = MA[10]; mab_10.y = MB[10];  mab_11.x = MA[11]; mab_11.y = MB[11];
    mab_12.x = MA[12]; mab_12.y = MB[12];  mab_13.x = MA[13]; mab_13.y = MB[13];
    mab_14.x = MA[14]; mab_14.y = MB[14];  mab_15.x = MA[15]; mab_15.y = MB[15];
    mab_16.x = MA[16]; mab_16.y = MB[16];  mab_17.x = MA[17]; mab_17.y = MB[17];
    mab_18.x = MA[18]; mab_18.y = MB[18];  mab_19.x = MA[19]; mab_19.y = MB[19];
    mab_20.x = MA[20]; mab_20.y = MB[20];

    const float b3A = b3p[rowA];
    const float b3B = b3p[rowB];

    // h state as SGPR pairs (low word = hs bits) + cell state
    long hsL_0 = 0, hsL_1 = 0, hsL_2 = 0, hsL_3 = 0, hsL_4 = 0, hsL_5 = 0;
    long hsL_6 = 0, hsL_7 = 0, hsL_8 = 0, hsL_9 = 0, hsL_10 = 0, hsL_11 = 0;
    long hsL_12 = 0, hsL_13 = 0, hsL_14 = 0, hsL_15 = 0, hsL_16 = 0;
    long hsL_17 = 0, hsL_18 = 0, hsL_19 = 0, hsL_20 = 0;
    float c = 0.0f;

    // zx chunk registers (waves 0/1): current chunk = 4 groups x 2 rows
    const float* baseA = zxG + rowA * 4;
    const float* baseB = zxG + rowB * 4;
    float4 cA0, cA1, cA2, cA3, cB0, cB1, cB2, cB3;
    if (wid < 2) {
        cA0 = LDG4(baseA + 0 * GSTRIDE); cA1 = LDG4(baseA + 1 * GSTRIDE);
        cA2 = LDG4(baseA + 2 * GSTRIDE); cA3 = LDG4(baseA + 3 * GSTRIDE);
        cB0 = LDG4(baseB + 0 * GSTRIDE); cB1 = LDG4(baseB + 1 * GSTRIDE);
        cB2 = LDG4(baseB + 2 * GSTRIDE); cB3 = LDG4(baseB + 3 * GSTRIDE);
    }

#pragma unroll 1
    for (int i = 0; i <= NCHUNK; ++i) {
        // prefetch next chunk (clamped in-bounds; waits land a full chunk later)
        float4 nA0, nA1, nA2, nA3, nB0, nB1, nB2, nB3;
        if (wid < 2) {
            const int gn = (i + 1 < NCHUNK) ? (i + 1) : (NCHUNK - 1);
            const float* pA = baseA + (size_t)gn * 4 * GSTRIDE;
            const float* pB = baseB + (size_t)gn * 4 * GSTRIDE;
            nA0 = LDG4(pA + 0 * GSTRIDE); nA1 = LDG4(pA + 1 * GSTRIDE);
            nA2 = LDG4(pA + 2 * GSTRIDE); nA3 = LDG4(pA + 3 * GSTRIDE);
            nB0 = LDG4(pB + 0 * GSTRIDE); nB1 = LDG4(pB + 1 * GSTRIDE);
            nB2 = LDG4(pB + 2 * GSTRIDE); nB3 = LDG4(pB + 3 * GSTRIDE);

            if (i < NCHUNK) {
                float* pp = &part[wid][i & 1][0][0];
                W01_STEP(0,  cA0.x, cB0.x) W01_STEP(1,  cA0.y, cB0.y)
                W01_STEP(2,  cA0.z, cB0.z) W01_STEP(3,  cA0.w, cB0.w)
                W01_STEP(4,  cA1.x, cB1.x) W01_STEP(5,  cA1.y, cB1.y)
                W01_STEP(6,  cA1.z, cB1.z) W01_STEP(7,  cA1.w, cB1.w)
                W01_STEP(8,  cA2.x, cB2.x) W01_STEP(9,  cA2.y, cB2.y)
                W01_STEP(10, cA2.z, cB2.z) W01_STEP(11, cA2.w, cB2.w)
                W01_STEP(12, cA3.x, cB3.x) W01_STEP(13, cA3.y, cB3.y)
                W01_STEP(14, cA3.z, cB3.z) W01_STEP(15, cA3.w, cB3.w)
            }
        } else if (i >= 1) {
            const int buf = (i - 1) & 1;
            const int tbase = (i - 1) * CHUNK;
            const float* p0 = &part[0][buf][0][0];
            const float* p1 = &part[1][buf][0][0];
            W2_STEP(0)  W2_STEP(1)  W2_STEP(2)  W2_STEP(3)
            W2_STEP(4)  W2_STEP(5)  W2_STEP(6)  W2_STEP(7)
            W2_STEP(8)  W2_STEP(9)  W2_STEP(10) W2_STEP(11)
            W2_STEP(12) W2_STEP(13) W2_STEP(14) W2_STEP(15)
        }
        __syncthreads();
        if (wid < 2) {
            cA0 = nA0; cA1 = nA1; cA2 = nA2; cA3 = nA3;
            cB0 = nB0; cB1 = nB1; cB2 = nB2; cB3 = nB3;
        }
    }
}

// ---------------------------------------------------------------------------
// K4: final linear: out[t] = h3[t] @ W3.T + bl3   (W3: [2,21])
// ---------------------------------------------------------------------------
__global__ void out_kernel(const float* __restrict__ h3, const float* __restrict__ W3,
                           const float* __restrict__ bl3, float* __restrict__ out)
{
    int t = blockIdx.x * blockDim.x + threadIdx.x;
    if (t >= T_LEN) return;
    float s0 = bl3[0], s1 = bl3[1];
#pragma unroll
    for (int kq = 0; kq < HDIM; ++kq) {
        float h = h3[t * HDIM + kq];
        s0 = __builtin_fmaf(W3[kq], h, s0);
        s1 = __builtin_fmaf(W3[HDIM + kq], h, s1);
    }
    out[t * 2 + 0] = s0;
    out[t * 2 + 1] = s1;
}

extern "C" void kernel_launch(void* const* d_in, const int* in_sizes, int n_in,
                              void* d_out, int out_size, void* d_ws, size_t ws_size,
                              hipStream_t stream) {
    const float* src  = (const float*)d_in[0];
    const float* Wih1 = (const float*)d_in[1];
    const float* Whh1 = (const float*)d_in[2];
    const float* b1   = (const float*)d_in[3];
    const float* W1   = (const float*)d_in[4];
    const float* bl1  = (const float*)d_in[5];
    const float* Wih2 = (const float*)d_in[6];
    const float* Whh2 = (const float*)d_in[7];
    const float* b2   = (const float*)d_in[8];
    const float* W2   = (const float*)d_in[9];
    const float* bl2  = (const float*)d_in[10];
    const float* Wih3 = (const float*)d_in[11];
    const float* Whh3 = (const float*)d_in[12];
    const float* b3   = (const float*)d_in[13];
    const float* W3   = (const float*)d_in[14];
    const float* bl3  = (const float*)d_in[15];
    float* out = (float*)d_out;

    float* ws   = (float*)d_ws;
    float* zxG1 = ws;
    float* zxG2 = zxG1 + (size_t)T_LEN * GDIM;
    float* h3   = zxG2 + (size_t)T_LEN * GDIM;
    float* M1   = h3   + (size_t)T_LEN * HDIM;
    float* M2   = M1   + GDIM * HDIM;
    float* b3p  = M2   + GDIM * HDIM;

    zx12_kernel<<<(T_LEN * GDIM + 255) / 256, 256, 0, stream>>>(
        src, Wih1, b1, Wih2, b2, zxG1, zxG2);
    fold_kernel<<<(GDIM * HDIM + 255) / 256, 256, 0, stream>>>(
        Wih3, W1, bl1, W2, bl2, b3, M1, M2, b3p);
    fused_scan_kernel<<<1, 192, 0, stream>>>(
        zxG1, Whh1, M1, zxG2, Whh2, M2, Whh3, b3p, h3);
    out_kernel<<<(T_LEN + 255) / 256, 256, 0, stream>>>(h3, W3, bl3, out);
}

// Round 15
// 2044.990 us; speedup vs baseline: 2.1592x; 1.1181x over previous
//
#include <hip/hip_runtime.h>
#include <hip/hip_bf16.h>

// Problem constants (from reference): T=8192 steps, batch=1, H=21 hidden.
#define T_LEN 8192
#define HDIM  21
#define GDIM  84           // 4*H gate rows
#define NGRP  (T_LEN / 4)  // 2048 groups of 4 timesteps
#define GSTRIDE (GDIM * 4) // 336 floats per group block
#define CHUNK 16           // steps per fused superstep (4 groups)
#define NCHUNK (T_LEN / CHUNK) // 512

#define LOG2E      1.4426950408889634f
#define TWO_LOG2E  2.8853900817779268f

typedef float floatx2 __attribute__((ext_vector_type(2)));
typedef unsigned u32x2 __attribute__((ext_vector_type(2)));

// packed FMA: acc.{x,y} += w.{x,y} * hs(low 32 bits of SGPR pair, both halves)
#define PKFMA(acc_, w_, h_)                                                \
    asm("v_pk_fma_f32 %0, %1, %2, %0 op_sel_hi:[1,0,1]"                    \
        : "+v"(acc_) : "v"(w_), "s"(h_))

__device__ __forceinline__ float rcp_fast(float x) {
    return __builtin_amdgcn_rcpf(x);     // v_rcp_f32, ~1ulp
}
__device__ __forceinline__ float exp2_fast(float x) {   // 2^x
    float r; asm("v_exp_f32 %0, %1" : "=v"(r) : "v"(x)); return r;
}
__device__ __forceinline__ float exp2n_fast(float x) {  // 2^(-x)
    float r; asm("v_exp_f32 %0, -%1" : "=v"(r) : "v"(x)); return r;
}
// inputs pre-scaled by log2(e): sigm2(x) == sigmoid(x/log2e)
__device__ __forceinline__ float sigm2(float x) {
    return rcp_fast(1.0f + exp2n_fast(x));   // x->+inf: 1 ; x->-inf: 0
}

// ---------------------------------------------------------------------------
// K1: parallel input projections, GROUPED output zxG[g][j][q] (coalesced),
// PRE-SCALED by log2(e) for the exp2-domain gate accumulate.
// ---------------------------------------------------------------------------
__global__ void zx12_kernel(const float* __restrict__ src,
                            const float* __restrict__ Wih1, const float* __restrict__ b1,
                            const float* __restrict__ Wih2, const float* __restrict__ b2,
                            float* __restrict__ zxG1, float* __restrict__ zxG2)
{
    int n = blockIdx.x * blockDim.x + threadIdx.x;
    if (n >= T_LEN * GDIM) return;
    unsigned g = (unsigned)n / GSTRIDE;
    unsigned r = (unsigned)n - g * GSTRIDE;
    unsigned j = r >> 2;
    unsigned t = (g << 2) | (r & 3);
    float4 s = *reinterpret_cast<const float4*>(src + 4 * t);
    float z1 = b1[j];
    z1 = __builtin_fmaf(Wih1[j * 3 + 0], s.x, z1);
    z1 = __builtin_fmaf(Wih1[j * 3 + 1], s.z, z1);
    z1 = __builtin_fmaf(Wih1[j * 3 + 2], s.w, z1);
    float z2 = b2[j];
    z2 = __builtin_fmaf(Wih2[j * 3 + 0], s.y, z2);
    z2 = __builtin_fmaf(Wih2[j * 3 + 1], s.z, z2);
    z2 = __builtin_fmaf(Wih2[j * 3 + 2], s.w, z2);
    zxG1[n] = z1 * LOG2E;
    zxG2[n] = z2 * LOG2E;
}

// ---------------------------------------------------------------------------
// K2: fold linear layers into LSTM3's input projection (unscaled; scaling
// happens at register load in the fused kernel).
// ---------------------------------------------------------------------------
__global__ void fold_kernel(const float* __restrict__ Wih3,
                            const float* __restrict__ W1, const float* __restrict__ bl1,
                            const float* __restrict__ W2, const float* __restrict__ bl2,
                            const float* __restrict__ b3,
                            float* __restrict__ M1, float* __restrict__ M2,
                            float* __restrict__ b3p)
{
    int idx = blockIdx.x * blockDim.x + threadIdx.x;
    if (idx < GDIM * HDIM) {
        int j = idx / HDIM, k = idx - j * HDIM;
        M1[idx] = Wih3[j * 50 + 0] * W1[k];
        float s = 0.0f;
        for (int m = 0; m < 49; ++m)
            s = __builtin_fmaf(Wih3[j * 50 + 1 + m], W2[m * HDIM + k], s);
        M2[idx] = s;
    }
    if (idx < GDIM) {
        float s = b3[idx] + Wih3[idx * 50 + 0] * bl1[0];
        for (int m = 0; m < 49; ++m)
            s = __builtin_fmaf(Wih3[idx * 50 + 1 + m], bl2[m], s);
        b3p[idx] = s;
    }
}

// ---------------------------------------------------------------------------
// K3: CHUNKED fused 3-LSTM scan, packed-FMA + permlane-swap edition.
//   wave0 = LSTM1, wave1 = LSTM2 (+ M*h projection into LDS, pk-paired)
//   wave2 = LSTM3, one chunk behind.
// Cross-half p exchange via __builtin_amdgcn_permlane32_swap (documented
// intrinsic, returns both swapped registers) — the R14 hand-asm dual "+v"
// form could alias both operands to one VGPR and corrupted pSw. The
// combine (x+y)-p is robust to either swap-direction convention.
// ---------------------------------------------------------------------------
#define RLI(h_, l_) __builtin_amdgcn_readlane(__float_as_int(h_), 32 + (l_))

#define BCAST_H(h_)                                                        \
    hsL_0  = (unsigned)RLI(h_, 0);  hsL_1  = (unsigned)RLI(h_, 1);         \
    hsL_2  = (unsigned)RLI(h_, 2);  hsL_3  = (unsigned)RLI(h_, 3);         \
    hsL_4  = (unsigned)RLI(h_, 4);  hsL_5  = (unsigned)RLI(h_, 5);         \
    hsL_6  = (unsigned)RLI(h_, 6);  hsL_7  = (unsigned)RLI(h_, 7);         \
    hsL_8  = (unsigned)RLI(h_, 8);  hsL_9  = (unsigned)RLI(h_, 9);         \
    hsL_10 = (unsigned)RLI(h_, 10); hsL_11 = (unsigned)RLI(h_, 11);        \
    hsL_12 = (unsigned)RLI(h_, 12); hsL_13 = (unsigned)RLI(h_, 13);        \
    hsL_14 = (unsigned)RLI(h_, 14); hsL_15 = (unsigned)RLI(h_, 15);        \
    hsL_16 = (unsigned)RLI(h_, 16); hsL_17 = (unsigned)RLI(h_, 17);        \
    hsL_18 = (unsigned)RLI(h_, 18); hsL_19 = (unsigned)RLI(h_, 19);        \
    hsL_20 = (unsigned)RLI(h_, 20);

// gates from zA_,zB_ (log2e-scaled); updates c; defines hW; broadcasts hsL_*
#define STEP_CORE(zA_, zB_)                                                \
        floatx2 q0, q1, q2;                                                \
        q0.x = (zA_); q0.y = (zB_);                                        \
        q1 = (floatx2)0.0f; q2 = (floatx2)0.0f;                            \
        PKFMA(q0, wab_0,  hsL_0);                                          \
        PKFMA(q1, wab_7,  hsL_7);                                          \
        PKFMA(q2, wab_14, hsL_14);                                         \
        PKFMA(q0, wab_1,  hsL_1);                                          \
        PKFMA(q1, wab_8,  hsL_8);                                          \
        PKFMA(q2, wab_15, hsL_15);                                         \
        PKFMA(q0, wab_2,  hsL_2);                                          \
        PKFMA(q1, wab_9,  hsL_9);                                          \
        PKFMA(q2, wab_16, hsL_16);                                         \
        PKFMA(q0, wab_3,  hsL_3);                                          \
        PKFMA(q1, wab_10, hsL_10);                                         \
        PKFMA(q2, wab_17, hsL_17);                                         \
        PKFMA(q0, wab_4,  hsL_4);                                          \
        PKFMA(q1, wab_11, hsL_11);                                         \
        PKFMA(q2, wab_18, hsL_18);                                         \
        PKFMA(q0, wab_5,  hsL_5);                                          \
        PKFMA(q1, wab_12, hsL_12);                                         \
        PKFMA(q2, wab_19, hsL_19);                                         \
        PKFMA(q0, wab_6,  hsL_6);                                          \
        PKFMA(q1, wab_13, hsL_13);                                         \
        PKFMA(q2, wab_20, hsL_20);                                         \
        floatx2 qt = (q0 + q1) + q2;                                       \
        float accA = qt.x;                                                 \
        float accB = qt.y;                                                 \
        float vA = sigm2(accA);                                            \
        float vB = __builtin_fmaf(mBc, sigm2(sB * accB), aB);              \
        float p_  = vA * vB;                                               \
        u32x2 rs_ = __builtin_amdgcn_permlane32_swap(                      \
            __float_as_uint(p_), __float_as_uint(p_), false, false);       \
        float pSw = (__uint_as_float(rs_.x) + __uint_as_float(rs_.y)) - p_;\
        c = __builtin_fmaf(vA, c, pSw);                                    \
        float th_ = __builtin_fmaf(                                        \
            -2.0f, rcp_fast(exp2_fast(TWO_LOG2E * c) + 1.0f), 1.0f);       \
        float hW  = vB * th_;                                              \
        BCAST_H(hW)

// waves 0/1: one step + packed folded projection into LDS at slot s_
#define W01_STEP(s_, zA_, zB_)                                             \
    {                                                                      \
        STEP_CORE(zA_, zB_)                                                \
        floatx2 r0, r1, r2;                                                \
        r0 = (floatx2)0.0f; r1 = (floatx2)0.0f; r2 = (floatx2)0.0f;        \
        PKFMA(r0, mab_0,  hsL_0);                                          \
        PKFMA(r1, mab_7,  hsL_7);                                          \
        PKFMA(r2, mab_14, hsL_14);                                         \
        PKFMA(r0, mab_1,  hsL_1);                                          \
        PKFMA(r1, mab_8,  hsL_8);                                          \
        PKFMA(r2, mab_15, hsL_15);                                         \
        PKFMA(r0, mab_2,  hsL_2);                                          \
        PKFMA(r1, mab_9,  hsL_9);                                          \
        PKFMA(r2, mab_16, hsL_16);                                         \
        PKFMA(r0, mab_3,  hsL_3);                                          \
        PKFMA(r1, mab_10, hsL_10);                                         \
        PKFMA(r2, mab_17, hsL_17);                                         \
        PKFMA(r0, mab_4,  hsL_4);                                          \
        PKFMA(r1, mab_11, hsL_11);                                         \
        PKFMA(r2, mab_18, hsL_18);                                         \
        PKFMA(r0, mab_5,  hsL_5);                                          \
        PKFMA(r1, mab_12, hsL_12);                                         \
        PKFMA(r2, mab_19, hsL_19);                                         \
        PKFMA(r0, mab_6,  hsL_6);                                          \
        PKFMA(r1, mab_13, hsL_13);                                         \
        PKFMA(r2, mab_20, hsL_20);                                         \
        floatx2 rt = (r0 + r1) + r2;                                       \
        if (act) {                                                         \
            pp[(s_) * GDIM + rowA] = rt.x;                                 \
            pp[(s_) * GDIM + rowB] = rt.y;                                 \
        }                                                                  \
    }

// wave2: one LSTM3 step from LDS partials at slot s_ (partials log2e-scaled)
#define W2_STEP(s_)                                                        \
    {                                                                      \
        float zA = b3A + p0[(s_) * GDIM + rowA] + p1[(s_) * GDIM + rowA];  \
        float zB = b3B + p0[(s_) * GDIM + rowB] + p1[(s_) * GDIM + rowB];  \
        STEP_CORE(zA, zB)                                                  \
        if (hi && act) h3out[(tbase + (s_)) * HDIM + k] = hW;              \
    }

#define LDG4(p_) (*reinterpret_cast<const float4*>(p_))

__global__ __launch_bounds__(192, 1)
void fused_scan_kernel(const float* __restrict__ zxG1, const float* __restrict__ Whh1,
                       const float* __restrict__ M1,
                       const float* __restrict__ zxG2, const float* __restrict__ Whh2,
                       const float* __restrict__ M2,
                       const float* __restrict__ Whh3, const float* __restrict__ b3p,
                       float* __restrict__ h3out)
{
    __shared__ float part[2][2][CHUNK][GDIM];   // [lstm][buf][step][row] = 21.5KB

    const int wid  = threadIdx.x >> 6;   // 0,1,2
    const int lane = threadIdx.x & 63;
    const int k = lane & 31;
    const bool hi = lane >= 32;
    const bool act = k < HDIM;
    const int kk = act ? k : 0;

    const int rowA = hi ? (HDIM + kk)     : kk;              // f : i  (sigmoid)
    const int rowB = hi ? (3 * HDIM + kk) : (2 * HDIM + kk); // o : g
    const float sB  = hi ? 1.0f : 2.0f;  // lo: tanh via 2*sigm(2x)-1 ; hi: sigm
    const float mBc = hi ? 1.0f : 2.0f;
    const float aB  = hi ? 0.0f : -1.0f;

    const float* Whh = (wid == 0) ? Whh1 : (wid == 1) ? Whh2 : Whh3;
    const float* zxG = (wid == 1) ? zxG2 : zxG1;                 // dummy for wid2
    const float* Mm  = (wid == 0) ? M1 : (wid == 1) ? M2 : Whh3; // dummy for wid2

    const float* WA = Whh + rowA * HDIM;
    const float* WB = Whh + rowB * HDIM;
    const float* MA = Mm  + rowA * HDIM;
    const float* MB = Mm  + rowB * HDIM;

    // recurrent weights packed (wa_j, wb_j), pre-scaled by log2e
    floatx2 wab_0,  wab_1,  wab_2,  wab_3,  wab_4,  wab_5,  wab_6;
    floatx2 wab_7,  wab_8,  wab_9,  wab_10, wab_11, wab_12, wab_13;
    floatx2 wab_14, wab_15, wab_16, wab_17, wab_18, wab_19, wab_20;
#define LOADW(j_) wab_##j_.x = WA[j_] * LOG2E; wab_##j_.y = WB[j_] * LOG2E;
    LOADW(0)  LOADW(1)  LOADW(2)  LOADW(3)  LOADW(4)  LOADW(5)  LOADW(6)
    LOADW(7)  LOADW(8)  LOADW(9)  LOADW(10) LOADW(11) LOADW(12) LOADW(13)
    LOADW(14) LOADW(15) LOADW(16) LOADW(17) LOADW(18) LOADW(19) LOADW(20)
#undef LOADW

    // projection weights packed (ma_j, mb_j), pre-scaled by log2e
    floatx2 mab_0,  mab_1,  mab_2,  mab_3,  mab_4,  mab_5,  mab_6;
    floatx2 mab_7,  mab_8,  mab_9,  mab_10, mab_11, mab_12, mab_13;
    floatx2 mab_14, mab_15, mab_16, mab_17, mab_18, mab_19, mab_20;
#define LOADM(j_) mab_##j_.x = MA[j_] * LOG2E; mab_##j_.y = MB[j_] * LOG2E;
    LOADM(0)  LOADM(1)  LOADM(2)  LOADM(3)  LOADM(4)  LOADM(5)  LOADM(6)
    LOADM(7)  LOADM(8)  LOADM(9)  LOADM(10) LOADM(11) LOADM(12) LOADM(13)
    LOADM(14) LOADM(15) LOADM(16) LOADM(17) LOADM(18) LOADM(19) LOADM(20)
#undef LOADM

    const float b3A = b3p[rowA] * LOG2E;
    const float b3B = b3p[rowB] * LOG2E;

    // h state as SGPR pairs (low word = hs bits) + cell state
    long hsL_0 = 0, hsL_1 = 0, hsL_2 = 0, hsL_3 = 0, hsL_4 = 0, hsL_5 = 0;
    long hsL_6 = 0, hsL_7 = 0, hsL_8 = 0, hsL_9 = 0, hsL_10 = 0, hsL_11 = 0;
    long hsL_12 = 0, hsL_13 = 0, hsL_14 = 0, hsL_15 = 0, hsL_16 = 0;
    long hsL_17 = 0, hsL_18 = 0, hsL_19 = 0, hsL_20 = 0;
    float c = 0.0f;

    // zx chunk registers (waves 0/1): current chunk = 4 groups x 2 rows
    const float* baseA = zxG + rowA * 4;
    const float* baseB = zxG + rowB * 4;
    float4 cA0, cA1, cA2, cA3, cB0, cB1, cB2, cB3;
    if (wid < 2) {
        cA0 = LDG4(baseA + 0 * GSTRIDE); cA1 = LDG4(baseA + 1 * GSTRIDE);
        cA2 = LDG4(baseA + 2 * GSTRIDE); cA3 = LDG4(baseA + 3 * GSTRIDE);
        cB0 = LDG4(baseB + 0 * GSTRIDE); cB1 = LDG4(baseB + 1 * GSTRIDE);
        cB2 = LDG4(baseB + 2 * GSTRIDE); cB3 = LDG4(baseB + 3 * GSTRIDE);
    }

#pragma unroll 1
    for (int i = 0; i <= NCHUNK; ++i) {
        // prefetch next chunk (clamped in-bounds; waits land a full chunk later)
        float4 nA0, nA1, nA2, nA3, nB0, nB1, nB2, nB3;
        if (wid < 2) {
            const int gn = (i + 1 < NCHUNK) ? (i + 1) : (NCHUNK - 1);
            const float* pA = baseA + (size_t)gn * 4 * GSTRIDE;
            const float* pB = baseB + (size_t)gn * 4 * GSTRIDE;
            nA0 = LDG4(pA + 0 * GSTRIDE); nA1 = LDG4(pA + 1 * GSTRIDE);
            nA2 = LDG4(pA + 2 * GSTRIDE); nA3 = LDG4(pA + 3 * GSTRIDE);
            nB0 = LDG4(pB + 0 * GSTRIDE); nB1 = LDG4(pB + 1 * GSTRIDE);
            nB2 = LDG4(pB + 2 * GSTRIDE); nB3 = LDG4(pB + 3 * GSTRIDE);

            if (i < NCHUNK) {
                float* pp = &part[wid][i & 1][0][0];
                W01_STEP(0,  cA0.x, cB0.x) W01_STEP(1,  cA0.y, cB0.y)
                W01_STEP(2,  cA0.z, cB0.z) W01_STEP(3,  cA0.w, cB0.w)
                W01_STEP(4,  cA1.x, cB1.x) W01_STEP(5,  cA1.y, cB1.y)
                W01_STEP(6,  cA1.z, cB1.z) W01_STEP(7,  cA1.w, cB1.w)
                W01_STEP(8,  cA2.x, cB2.x) W01_STEP(9,  cA2.y, cB2.y)
                W01_STEP(10, cA2.z, cB2.z) W01_STEP(11, cA2.w, cB2.w)
                W01_STEP(12, cA3.x, cB3.x) W01_STEP(13, cA3.y, cB3.y)
                W01_STEP(14, cA3.z, cB3.z) W01_STEP(15, cA3.w, cB3.w)
            }
        } else if (i >= 1) {
            const int buf = (i - 1) & 1;
            const int tbase = (i - 1) * CHUNK;
            const float* p0 = &part[0][buf][0][0];
            const float* p1 = &part[1][buf][0][0];
            W2_STEP(0)  W2_STEP(1)  W2_STEP(2)  W2_STEP(3)
            W2_STEP(4)  W2_STEP(5)  W2_STEP(6)  W2_STEP(7)
            W2_STEP(8)  W2_STEP(9)  W2_STEP(10) W2_STEP(11)
            W2_STEP(12) W2_STEP(13) W2_STEP(14) W2_STEP(15)
        }
        __syncthreads();
        if (wid < 2) {
            cA0 = nA0; cA1 = nA1; cA2 = nA2; cA3 = nA3;
            cB0 = nB0; cB1 = nB1; cB2 = nB2; cB3 = nB3;
        }
    }
}

// ---------------------------------------------------------------------------
// K4: final linear: out[t] = h3[t] @ W3.T + bl3   (W3: [2,21])
// ---------------------------------------------------------------------------
__global__ void out_kernel(const float* __restrict__ h3, const float* __restrict__ W3,
                           const float* __restrict__ bl3, float* __restrict__ out)
{
    int t = blockIdx.x * blockDim.x + threadIdx.x;
    if (t >= T_LEN) return;
    float s0 = bl3[0], s1 = bl3[1];
#pragma unroll
    for (int kq = 0; kq < HDIM; ++kq) {
        float h = h3[t * HDIM + kq];
        s0 = __builtin_fmaf(W3[kq], h, s0);
        s1 = __builtin_fmaf(W3[HDIM + kq], h, s1);
    }
    out[t * 2 + 0] = s0;
    out[t * 2 + 1] = s1;
}

extern "C" void kernel_launch(void* const* d_in, const int* in_sizes, int n_in,
                              void* d_out, int out_size, void* d_ws, size_t ws_size,
                              hipStream_t stream) {
    const float* src  = (const float*)d_in[0];
    const float* Wih1 = (const float*)d_in[1];
    const float* Whh1 = (const float*)d_in[2];
    const float* b1   = (const float*)d_in[3];
    const float* W1   = (const float*)d_in[4];
    const float* bl1  = (const float*)d_in[5];
    const float* Wih2 = (const float*)d_in[6];
    const float* Whh2 = (const float*)d_in[7];
    const float* b2   = (const float*)d_in[8];
    const float* W2   = (const float*)d_in[9];
    const float* bl2  = (const float*)d_in[10];
    const float* Wih3 = (const float*)d_in[11];
    const float* Whh3 = (const float*)d_in[12];
    const float* b3   = (const float*)d_in[13];
    const float* W3   = (const float*)d_in[14];
    const float* bl3  = (const float*)d_in[15];
    float* out = (float*)d_out;

    float* ws   = (float*)d_ws;
    float* zxG1 = ws;
    float* zxG2 = zxG1 + (size_t)T_LEN * GDIM;
    float* h3   = zxG2 + (size_t)T_LEN * GDIM;
    float* M1   = h3   + (size_t)T_LEN * HDIM;
    float* M2   = M1   + GDIM * HDIM;
    float* b3p  = M2   + GDIM * HDIM;

    zx12_kernel<<<(T_LEN * GDIM + 255) / 256, 256, 0, stream>>>(
        src, Wih1, b1, Wih2, b2, zxG1, zxG2);
    fold_kernel<<<(GDIM * HDIM + 255) / 256, 256, 0, stream>>>(
        Wih3, W1, bl1, W2, bl2, b3, M1, M2, b3p);
    fused_scan_kernel<<<1, 192, 0, stream>>>(
        zxG1, Whh1, M1, zxG2, Whh2, M2, Whh3, b3p, h3);
    out_kernel<<<(T_LEN + 255) / 256, 256, 0, stream>>>(h3, W3, bl3, out);
}

// Round 16
// 1974.731 us; speedup vs baseline: 2.2360x; 1.0356x over previous
//
#include <hip/hip_runtime.h>
#include <hip/hip_bf16.h>

// Problem constants (from reference): T=8192 steps, batch=1, H=21 hidden.
#define T_LEN 8192
#define HDIM  21
#define GDIM  84           // 4*H gate rows
#define NGRP  (T_LEN / 4)  // 2048 groups of 4 timesteps
#define GSTRIDE (GDIM * 4) // 336 floats per group block
#define CHUNK 16           // steps per fused superstep (4 groups)
#define NCHUNK (T_LEN / CHUNK) // 512

#define LOG2E      1.4426950408889634f
#define TWO_LOG2E  2.8853900817779268f

typedef float floatx2 __attribute__((ext_vector_type(2)));
typedef unsigned u32x2 __attribute__((ext_vector_type(2)));

// packed FMA: acc.{x,y} += w.{x,y} * hs(low 32 bits of SGPR pair, both halves)
#define PKFMA(acc_, w_, h_)                                                \
    asm("v_pk_fma_f32 %0, %1, %2, %0 op_sel_hi:[1,0,1]"                    \
        : "+v"(acc_) : "v"(w_), "s"(h_))

__device__ __forceinline__ float rcp_fast(float x) {
    return __builtin_amdgcn_rcpf(x);     // v_rcp_f32, ~1ulp
}
__device__ __forceinline__ float exp2_fast(float x) {   // 2^x
    float r; asm("v_exp_f32 %0, %1" : "=v"(r) : "v"(x)); return r;
}
__device__ __forceinline__ float exp2n_fast(float x) {  // 2^(-x)
    float r; asm("v_exp_f32 %0, -%1" : "=v"(r) : "v"(x)); return r;
}
// inputs pre-scaled by log2(e): sigm2(x) == sigmoid(x/log2e)
__device__ __forceinline__ float sigm2(float x) {
    return rcp_fast(1.0f + exp2n_fast(x));   // x->+inf: 1 ; x->-inf: 0
}

// ---------------------------------------------------------------------------
// K1: parallel input projections, GROUPED output zxG[g][j][q] (coalesced).
// Rows pre-scaled by log2e; g-rows (2H..3H-1) additionally x2 so the tanh
// doubling is folded into the data (STEP has no sB multiply).
// ---------------------------------------------------------------------------
__global__ void zx12_kernel(const float* __restrict__ src,
                            const float* __restrict__ Wih1, const float* __restrict__ b1,
                            const float* __restrict__ Wih2, const float* __restrict__ b2,
                            float* __restrict__ zxG1, float* __restrict__ zxG2)
{
    int n = blockIdx.x * blockDim.x + threadIdx.x;
    if (n >= T_LEN * GDIM) return;
    unsigned g = (unsigned)n / GSTRIDE;
    unsigned r = (unsigned)n - g * GSTRIDE;
    unsigned j = r >> 2;
    unsigned t = (g << 2) | (r & 3);
    float4 s = *reinterpret_cast<const float4*>(src + 4 * t);
    float z1 = b1[j];
    z1 = __builtin_fmaf(Wih1[j * 3 + 0], s.x, z1);
    z1 = __builtin_fmaf(Wih1[j * 3 + 1], s.z, z1);
    z1 = __builtin_fmaf(Wih1[j * 3 + 2], s.w, z1);
    float z2 = b2[j];
    z2 = __builtin_fmaf(Wih2[j * 3 + 0], s.y, z2);
    z2 = __builtin_fmaf(Wih2[j * 3 + 1], s.z, z2);
    z2 = __builtin_fmaf(Wih2[j * 3 + 2], s.w, z2);
    float sc = (j >= 2 * HDIM && j < 3 * HDIM) ? TWO_LOG2E : LOG2E;
    zxG1[n] = z1 * sc;
    zxG2[n] = z2 * sc;
}

// ---------------------------------------------------------------------------
// K2: fold linear layers into LSTM3's input projection (unscaled; scaling
// happens at register load in the fused kernel).
// ---------------------------------------------------------------------------
__global__ void fold_kernel(const float* __restrict__ Wih3,
                            const float* __restrict__ W1, const float* __restrict__ bl1,
                            const float* __restrict__ W2, const float* __restrict__ bl2,
                            const float* __restrict__ b3,
                            float* __restrict__ M1, float* __restrict__ M2,
                            float* __restrict__ b3p)
{
    int idx = blockIdx.x * blockDim.x + threadIdx.x;
    if (idx < GDIM * HDIM) {
        int j = idx / HDIM, k = idx - j * HDIM;
        M1[idx] = Wih3[j * 50 + 0] * W1[k];
        float s = 0.0f;
        for (int m = 0; m < 49; ++m)
            s = __builtin_fmaf(Wih3[j * 50 + 1 + m], W2[m * HDIM + k], s);
        M2[idx] = s;
    }
    if (idx < GDIM) {
        float s = b3[idx] + Wih3[idx * 50 + 0] * bl1[0];
        for (int m = 0; m < 49; ++m)
            s = __builtin_fmaf(Wih3[idx * 50 + 1 + m], bl2[m], s);
        b3p[idx] = s;
    }
}

// ---------------------------------------------------------------------------
// K3: CHUNKED fused 3-LSTM scan.
//   wave0 = LSTM1, wave1 = LSTM2 (+ M*h projection into LDS, pk-paired)
//   wave2 = LSTM3, one chunk behind.
// This round: (1) proj partials stored as ONE float2 per lane at slot
// 2*kk+hi (ds_write_b64); wave2 reads its own slot back (2 loads + 1 pk_add
// instead of 4 loads + 4 adds) — reader/writer lane maps are identical.
// (2) b3p folded into wave0's proj init. (3) g-row doubling folded into
// weights/zx (no sB multiply in STEP).
// ---------------------------------------------------------------------------
#define RLI(h_, l_) __builtin_amdgcn_readlane(__float_as_int(h_), 32 + (l_))

#define BCAST_H(h_)                                                        \
    hsL_0  = (unsigned)RLI(h_, 0);  hsL_1  = (unsigned)RLI(h_, 1);         \
    hsL_2  = (unsigned)RLI(h_, 2);  hsL_3  = (unsigned)RLI(h_, 3);         \
    hsL_4  = (unsigned)RLI(h_, 4);  hsL_5  = (unsigned)RLI(h_, 5);         \
    hsL_6  = (unsigned)RLI(h_, 6);  hsL_7  = (unsigned)RLI(h_, 7);         \
    hsL_8  = (unsigned)RLI(h_, 8);  hsL_9  = (unsigned)RLI(h_, 9);         \
    hsL_10 = (unsigned)RLI(h_, 10); hsL_11 = (unsigned)RLI(h_, 11);        \
    hsL_12 = (unsigned)RLI(h_, 12); hsL_13 = (unsigned)RLI(h_, 13);        \
    hsL_14 = (unsigned)RLI(h_, 14); hsL_15 = (unsigned)RLI(h_, 15);        \
    hsL_16 = (unsigned)RLI(h_, 16); hsL_17 = (unsigned)RLI(h_, 17);        \
    hsL_18 = (unsigned)RLI(h_, 18); hsL_19 = (unsigned)RLI(h_, 19);        \
    hsL_20 = (unsigned)RLI(h_, 20);

// gates from zA_,zB_ (log2e-scaled, g-rows pre-doubled); updates c; hW; bcast
#define STEP_CORE(zA_, zB_)                                                \
        floatx2 q0, q1, q2;                                                \
        q0.x = (zA_); q0.y = (zB_);                                        \
        q1 = (floatx2)0.0f; q2 = (floatx2)0.0f;                            \
        PKFMA(q0, wab_0,  hsL_0);                                          \
        PKFMA(q1, wab_7,  hsL_7);                                          \
        PKFMA(q2, wab_14, hsL_14);                                         \
        PKFMA(q0, wab_1,  hsL_1);                                          \
        PKFMA(q1, wab_8,  hsL_8);                                          \
        PKFMA(q2, wab_15, hsL_15);                                         \
        PKFMA(q0, wab_2,  hsL_2);                                          \
        PKFMA(q1, wab_9,  hsL_9);                                          \
        PKFMA(q2, wab_16, hsL_16);                                         \
        PKFMA(q0, wab_3,  hsL_3);                                          \
        PKFMA(q1, wab_10, hsL_10);                                         \
        PKFMA(q2, wab_17, hsL_17);                                         \
        PKFMA(q0, wab_4,  hsL_4);                                          \
        PKFMA(q1, wab_11, hsL_11);                                         \
        PKFMA(q2, wab_18, hsL_18);                                         \
        PKFMA(q0, wab_5,  hsL_5);                                          \
        PKFMA(q1, wab_12, hsL_12);                                         \
        PKFMA(q2, wab_19, hsL_19);                                         \
        PKFMA(q0, wab_6,  hsL_6);                                          \
        PKFMA(q1, wab_13, hsL_13);                                         \
        PKFMA(q2, wab_20, hsL_20);                                         \
        floatx2 qt = (q0 + q1) + q2;                                       \
        float accA = qt.x;                                                 \
        float accB = qt.y;                                                 \
        float vA = sigm2(accA);                                            \
        float vB = __builtin_fmaf(mBc, sigm2(accB), aB);                   \
        float p_  = vA * vB;                                               \
        u32x2 rs_ = __builtin_amdgcn_permlane32_swap(                      \
            __float_as_uint(p_), __float_as_uint(p_), false, false);       \
        float pSw = (__uint_as_float(rs_.x) + __uint_as_float(rs_.y)) - p_;\
        c = __builtin_fmaf(vA, c, pSw);                                    \
        float th_ = __builtin_fmaf(                                        \
            -2.0f, rcp_fast(exp2_fast(TWO_LOG2E * c) + 1.0f), 1.0f);       \
        float hW  = vB * th_;                                              \
        BCAST_H(hW)

// waves 0/1: one step + packed folded projection into LDS at slot_
#define W01_STEP(s_, zA_, zB_)                                             \
    {                                                                      \
        STEP_CORE(zA_, zB_)                                                \
        floatx2 r0 = rbias, r1 = (floatx2)0.0f, r2 = (floatx2)0.0f;        \
        PKFMA(r0, mab_0,  hsL_0);                                          \
        PKFMA(r1, mab_7,  hsL_7);                                          \
        PKFMA(r2, mab_14, hsL_14);                                         \
        PKFMA(r0, mab_1,  hsL_1);                                          \
        PKFMA(r1, mab_8,  hsL_8);                                          \
        PKFMA(r2, mab_15, hsL_15);                                         \
        PKFMA(r0, mab_2,  hsL_2);                                          \
        PKFMA(r1, mab_9,  hsL_9);                                          \
        PKFMA(r2, mab_16, hsL_16);                                         \
        PKFMA(r0, mab_3,  hsL_3);                                          \
        PKFMA(r1, mab_10, hsL_10);                                         \
        PKFMA(r2, mab_17, hsL_17);                                         \
        PKFMA(r0, mab_4,  hsL_4);                                          \
        PKFMA(r1, mab_11, hsL_11);                                         \
        PKFMA(r2, mab_18, hsL_18);                                         \
        PKFMA(r0, mab_5,  hsL_5);                                          \
        PKFMA(r1, mab_12, hsL_12);                                         \
        PKFMA(r2, mab_19, hsL_19);                                         \
        PKFMA(r0, mab_6,  hsL_6);                                          \
        PKFMA(r1, mab_13, hsL_13);                                         \
        PKFMA(r2, mab_20, hsL_20);                                         \
        if (act) pp[(s_) * 42 + slot] = (r0 + r1) + r2;                    \
    }

// wave2: one LSTM3 step from LDS partials at slot (bias pre-folded by wave0)
#define W2_STEP(s_)                                                        \
    {                                                                      \
        floatx2 pz = pp0[(s_) * 42 + slot] + pp1[(s_) * 42 + slot];        \
        STEP_CORE(pz.x, pz.y)                                              \
        if (hi && act) h3out[(tbase + (s_)) * HDIM + k] = hW;              \
    }

#define LDG4(p_) (*reinterpret_cast<const float4*>(p_))

__global__ __launch_bounds__(192, 1)
void fused_scan_kernel(const float* __restrict__ zxG1, const float* __restrict__ Whh1,
                       const float* __restrict__ M1,
                       const float* __restrict__ zxG2, const float* __restrict__ Whh2,
                       const float* __restrict__ M2,
                       const float* __restrict__ Whh3, const float* __restrict__ b3p,
                       float* __restrict__ h3out)
{
    __shared__ floatx2 part[2][2][CHUNK][42];   // [lstm][buf][step][slot] = 21.5KB

    const int wid  = threadIdx.x >> 6;   // 0,1,2
    const int lane = threadIdx.x & 63;
    const int k = lane & 31;
    const bool hi = lane >= 32;
    const bool act = k < HDIM;
    const int kk = act ? k : 0;
    const int slot = kk * 2 + (hi ? 1 : 0);

    const int rowA = hi ? (HDIM + kk)     : kk;              // f : i  (sigmoid)
    const int rowB = hi ? (3 * HDIM + kk) : (2 * HDIM + kk); // o : g
    const float mBc = hi ? 1.0f : 2.0f;  // lo: tanh = 2*sigm2(2x)-1 (2x folded)
    const float aB  = hi ? 0.0f : -1.0f;
    const float scB = hi ? LOG2E : TWO_LOG2E;  // g-row doubling fold

    const float* Whh = (wid == 0) ? Whh1 : (wid == 1) ? Whh2 : Whh3;
    const float* zxG = (wid == 1) ? zxG2 : zxG1;                 // dummy for wid2
    const float* Mm  = (wid == 0) ? M1 : (wid == 1) ? M2 : Whh3; // dummy for wid2

    const float* WA = Whh + rowA * HDIM;
    const float* WB = Whh + rowB * HDIM;
    const float* MA = Mm  + rowA * HDIM;
    const float* MB = Mm  + rowB * HDIM;

    // recurrent weights packed (wa_j, wb_j), pre-scaled (g-rows x2)
    floatx2 wab_0,  wab_1,  wab_2,  wab_3,  wab_4,  wab_5,  wab_6;
    floatx2 wab_7,  wab_8,  wab_9,  wab_10, wab_11, wab_12, wab_13;
    floatx2 wab_14, wab_15, wab_16, wab_17, wab_18, wab_19, wab_20;
#define LOADW(j_) wab_##j_.x = WA[j_] * LOG2E; wab_##j_.y = WB[j_] * scB;
    LOADW(0)  LOADW(1)  LOADW(2)  LOADW(3)  LOADW(4)  LOADW(5)  LOADW(6)
    LOADW(7)  LOADW(8)  LOADW(9)  LOADW(10) LOADW(11) LOADW(12) LOADW(13)
    LOADW(14) LOADW(15) LOADW(16) LOADW(17) LOADW(18) LOADW(19) LOADW(20)
#undef LOADW

    // projection weights packed (ma_j, mb_j), pre-scaled (g-rows x2)
    floatx2 mab_0,  mab_1,  mab_2,  mab_3,  mab_4,  mab_5,  mab_6;
    floatx2 mab_7,  mab_8,  mab_9,  mab_10, mab_11, mab_12, mab_13;
    floatx2 mab_14, mab_15, mab_16, mab_17, mab_18, mab_19, mab_20;
#define LOADM(j_) mab_##j_.x = MA[j_] * LOG2E; mab_##j_.y = MB[j_] * scB;
    LOADM(0)  LOADM(1)  LOADM(2)  LOADM(3)  LOADM(4)  LOADM(5)  LOADM(6)
    LOADM(7)  LOADM(8)  LOADM(9)  LOADM(10) LOADM(11) LOADM(12) LOADM(13)
    LOADM(14) LOADM(15) LOADM(16) LOADM(17) LOADM(18) LOADM(19) LOADM(20)
#undef LOADM

    // LSTM3 bias folded into wave0's proj accumulator init (wave1 adds 0)
    floatx2 rbias;
    rbias.x = (wid == 0) ? b3p[rowA] * LOG2E : 0.0f;
    rbias.y = (wid == 0) ? b3p[rowB] * scB   : 0.0f;

    // h state as SGPR pairs (low word = hs bits) + cell state
    long hsL_0 = 0, hsL_1 = 0, hsL_2 = 0, hsL_3 = 0, hsL_4 = 0, hsL_5 = 0;
    long hsL_6 = 0, hsL_7 = 0, hsL_8 = 0, hsL_9 = 0, hsL_10 = 0, hsL_11 = 0;
    long hsL_12 = 0, hsL_13 = 0, hsL_14 = 0, hsL_15 = 0, hsL_16 = 0;
    long hsL_17 = 0, hsL_18 = 0, hsL_19 = 0, hsL_20 = 0;
    float c = 0.0f;

    // zx chunk registers (waves 0/1): current chunk = 4 groups x 2 rows
    const float* baseA = zxG + rowA * 4;
    const float* baseB = zxG + rowB * 4;
    float4 cA0, cA1, cA2, cA3, cB0, cB1, cB2, cB3;
    if (wid < 2) {
        cA0 = LDG4(baseA + 0 * GSTRIDE); cA1 = LDG4(baseA + 1 * GSTRIDE);
        cA2 = LDG4(baseA + 2 * GSTRIDE); cA3 = LDG4(baseA + 3 * GSTRIDE);
        cB0 = LDG4(baseB + 0 * GSTRIDE); cB1 = LDG4(baseB + 1 * GSTRIDE);
        cB2 = LDG4(baseB + 2 * GSTRIDE); cB3 = LDG4(baseB + 3 * GSTRIDE);
    }

#pragma unroll 1
    for (int i = 0; i <= NCHUNK; ++i) {
        // prefetch next chunk (clamped in-bounds; waits land a full chunk later)
        float4 nA0, nA1, nA2, nA3, nB0, nB1, nB2, nB3;
        if (wid < 2) {
            const int gn = (i + 1 < NCHUNK) ? (i + 1) : (NCHUNK - 1);
            const float* pA = baseA + (size_t)gn * 4 * GSTRIDE;
            const float* pB = baseB + (size_t)gn * 4 * GSTRIDE;
            nA0 = LDG4(pA + 0 * GSTRIDE); nA1 = LDG4(pA + 1 * GSTRIDE);
            nA2 = LDG4(pA + 2 * GSTRIDE); nA3 = LDG4(pA + 3 * GSTRIDE);
            nB0 = LDG4(pB + 0 * GSTRIDE); nB1 = LDG4(pB + 1 * GSTRIDE);
            nB2 = LDG4(pB + 2 * GSTRIDE); nB3 = LDG4(pB + 3 * GSTRIDE);

            if (i < NCHUNK) {
                floatx2* pp = &part[wid][i & 1][0][0];
                W01_STEP(0,  cA0.x, cB0.x) W01_STEP(1,  cA0.y, cB0.y)
                W01_STEP(2,  cA0.z, cB0.z) W01_STEP(3,  cA0.w, cB0.w)
                W01_STEP(4,  cA1.x, cB1.x) W01_STEP(5,  cA1.y, cB1.y)
                W01_STEP(6,  cA1.z, cB1.z) W01_STEP(7,  cA1.w, cB1.w)
                W01_STEP(8,  cA2.x, cB2.x) W01_STEP(9,  cA2.y, cB2.y)
                W01_STEP(10, cA2.z, cB2.z) W01_STEP(11, cA2.w, cB2.w)
                W01_STEP(12, cA3.x, cB3.x) W01_STEP(13, cA3.y, cB3.y)
                W01_STEP(14, cA3.z, cB3.z) W01_STEP(15, cA3.w, cB3.w)
            }
        } else if (i >= 1) {
            const int buf = (i - 1) & 1;
            const int tbase = (i - 1) * CHUNK;
            const floatx2* pp0 = &part[0][buf][0][0];
            const floatx2* pp1 = &part[1][buf][0][0];
            W2_STEP(0)  W2_STEP(1)  W2_STEP(2)  W2_STEP(3)
            W2_STEP(4)  W2_STEP(5)  W2_STEP(6)  W2_STEP(7)
            W2_STEP(8)  W2_STEP(9)  W2_STEP(10) W2_STEP(11)
            W2_STEP(12) W2_STEP(13) W2_STEP(14) W2_STEP(15)
        }
        __syncthreads();
        if (wid < 2) {
            cA0 = nA0; cA1 = nA1; cA2 = nA2; cA3 = nA3;
            cB0 = nB0; cB1 = nB1; cB2 = nB2; cB3 = nB3;
        }
    }
}

// ---------------------------------------------------------------------------
// K4: final linear: out[t] = h3[t] @ W3.T + bl3   (W3: [2,21])
// ---------------------------------------------------------------------------
__global__ void out_kernel(const float* __restrict__ h3, const float* __restrict__ W3,
                           const float* __restrict__ bl3, float* __restrict__ out)
{
    int t = blockIdx.x * blockDim.x + threadIdx.x;
    if (t >= T_LEN) return;
    float s0 = bl3[0], s1 = bl3[1];
#pragma unroll
    for (int kq = 0; kq < HDIM; ++kq) {
        float h = h3[t * HDIM + kq];
        s0 = __builtin_fmaf(W3[kq], h, s0);
        s1 = __builtin_fmaf(W3[HDIM + kq], h, s1);
    }
    out[t * 2 + 0] = s0;
    out[t * 2 + 1] = s1;
}

extern "C" void kernel_launch(void* const* d_in, const int* in_sizes, int n_in,
                              void* d_out, int out_size, void* d_ws, size_t ws_size,
                              hipStream_t stream) {
    const float* src  = (const float*)d_in[0];
    const float* Wih1 = (const float*)d_in[1];
    const float* Whh1 = (const float*)d_in[2];
    const float* b1   = (const float*)d_in[3];
    const float* W1   = (const float*)d_in[4];
    const float* bl1  = (const float*)d_in[5];
    const float* Wih2 = (const float*)d_in[6];
    const float* Whh2 = (const float*)d_in[7];
    const float* b2   = (const float*)d_in[8];
    const float* W2   = (const float*)d_in[9];
    const float* bl2  = (const float*)d_in[10];
    const float* Wih3 = (const float*)d_in[11];
    const float* Whh3 = (const float*)d_in[12];
    const float* b3   = (const float*)d_in[13];
    const float* W3   = (const float*)d_in[14];
    const float* bl3  = (const float*)d_in[15];
    float* out = (float*)d_out;

    float* ws   = (float*)d_ws;
    float* zxG1 = ws;
    float* zxG2 = zxG1 + (size_t)T_LEN * GDIM;
    float* h3   = zxG2 + (size_t)T_LEN * GDIM;
    float* M1   = h3   + (size_t)T_LEN * HDIM;
    float* M2   = M1   + GDIM * HDIM;
    float* b3p  = M2   + GDIM * HDIM;

    zx12_kernel<<<(T_LEN * GDIM + 255) / 256, 256, 0, stream>>>(
        src, Wih1, b1, Wih2, b2, zxG1, zxG2);
    fold_kernel<<<(GDIM * HDIM + 255) / 256, 256, 0, stream>>>(
        Wih3, W1, bl1, W2, bl2, b3, M1, M2, b3p);
    fused_scan_kernel<<<1, 192, 0, stream>>>(
        zxG1, Whh1, M1, zxG2, Whh2, M2, Whh3, b3p, h3);
    out_kernel<<<(T_LEN + 255) / 256, 256, 0, stream>>>(h3, W3, bl3, out);
}